// Round 9
// baseline (2199.050 us; speedup 1.0000x reference)
//
#include <hip/hip_runtime.h>
#include <math.h>

// ============================================================================
// PCA + LSTM encoder/decoder on MI355X.
//  - GEMMs: mfma_f32_16x16x32_bf16, 3-term split-bf16 (hi/lo) ~ fp32 accuracy.
//  - Encoder x@K precomputed for all 64 steps in ONE GEMM (zx, bf16 hi/lo).
//  - All 88 recurrent steps in ONE persistent cooperative kernel.
//    * R9 KEY CHANGE: W_hi lives in LDS (128 KiB/block, loaded once via
//      global_load_lds). R7/R8 proved the compiler will NOT keep 128 weight
//      VGPRs resident (VGPR_Count pinned at 128, spill-by-reload every step).
//      LDS is the on-chip store it cannot evict. W_lo (32 MiB chip-wide,
//      4 MiB/XCD = L2-resident) streams from global each step.
//    * At s==64: block-local transmute W := resplit(R + K) -> LDS hi + wl2
//      (scratch region) lo. Kmat read fp32 directly, once.
//    * Custom barrier: RELAXED spin + ONE acquire fence at exit (R7-proven).
//  - Workspace: 177 MiB envelope proven in R1-R8 + 4 KiB barrier state.
// ============================================================================

typedef unsigned short US;
typedef __attribute__((ext_vector_type(8))) short bf16x8;
typedef __attribute__((ext_vector_type(4))) float f32x4;

typedef __attribute__((address_space(3))) unsigned int as3_uint;
typedef __attribute__((address_space(1))) unsigned int as1_uint;

#define MFMA(a, b, c) __builtin_amdgcn_mfma_f32_16x16x32_bf16(a, b, c, 0, 0, 0)

__device__ __forceinline__ US f2bf(float x) {   // RNE fp32 -> bf16 bits
  unsigned int u = __float_as_uint(x);
  unsigned int r = 0x7FFFu + ((u >> 16) & 1u);
  return (US)((u + r) >> 16);
}
__device__ __forceinline__ float bf2f(US u) {
  return __uint_as_float(((unsigned int)u) << 16);
}

__device__ __forceinline__ void gl_lds16(const US* g, US* l) {
  __builtin_amdgcn_global_load_lds((const as1_uint*)g, (as3_uint*)l, 16, 0, 0);
}

// ---- elementwise fp32 -> bf16 hi/lo split ----------------------------------
__global__ __launch_bounds__(256) void split_kernel(
    const float* __restrict__ in, US* __restrict__ hi, US* __restrict__ lo, int n4)
{
  int i = blockIdx.x * 256 + threadIdx.x;
  if (i >= n4) return;
  float4 v = reinterpret_cast<const float4*>(in)[i];
  US h0 = f2bf(v.x), h1 = f2bf(v.y), h2 = f2bf(v.z), h3 = f2bf(v.w);
  ushort4 hv = make_ushort4(h0, h1, h2, h3);
  ushort4 lv = make_ushort4(f2bf(v.x - bf2f(h0)), f2bf(v.y - bf2f(h1)),
                            f2bf(v.z - bf2f(h2)), f2bf(v.w - bf2f(h3)));
  reinterpret_cast<ushort4*>(hi)[i] = hv;
  reinterpret_cast<ushort4*>(lo)[i] = lv;
}

// ---- zero initial h frag buffers + barrier state ---------------------------
__global__ void zero_kernel(US* __restrict__ h0, US* __restrict__ l0,
                            unsigned* __restrict__ bar)
{
  int i = blockIdx.x * 256 + threadIdx.x;   // grid covers 65536 exactly
  h0[i] = 0; l0[i] = 0;
  if (i < 1024) bar[i] = 0;
}

// ---- mproj[j] = sum_k mean[k] * comp[j][k] ---------------------------------
__global__ __launch_bounds__(256) void mproj_kernel(
    const float* __restrict__ mean, const float* __restrict__ comp,
    float* __restrict__ mproj)
{
  int j = blockIdx.x;
  const float* row = comp + (size_t)j * 2048;
  float s = 0.f;
  for (int k = threadIdx.x; k < 2048; k += 256) s += mean[k] * row[k];
  __shared__ float ss[4];
  #pragma unroll
  for (int o = 32; o > 0; o >>= 1) s += __shfl_down(s, o, 64);
  if ((threadIdx.x & 63) == 0) ss[threadIdx.x >> 6] = s;
  __syncthreads();
  if (threadIdx.x == 0) mproj[j] = ss[0] + ss[1] + ss[2] + ss[3];
}

// ---- build KT[j'][k] row-major gate-interleaved transpose (for zx GEMM) ----
__global__ __launch_bounds__(256) void build_kt(
    const float* __restrict__ src, US* __restrict__ t_hi, US* __restrict__ t_lo)
{
  __shared__ float tile[64][65];
  const int jblk = blockIdx.x >> 5;
  const int kblk = blockIdx.x & 31;
  const int j0 = jblk * 64;
  const int u0 = j0 >> 2;
  const int k0 = kblk * 64;
  const int tid = threadIdx.x;
  const int cc = tid & 63;
  const int g = cc >> 4, uo = cc & 15;
  const int col = g * 2048 + u0 + uo;
  const int kl0 = tid >> 6;
  #pragma unroll
  for (int r = 0; r < 16; ++r) {
    int kl = r * 4 + kl0;
    tile[4 * uo + g][kl] = src[(size_t)(k0 + kl) * 8192 + col];
  }
  __syncthreads();
  const int kl = tid & 63;
  const int jl0 = tid >> 6;
  #pragma unroll
  for (int r = 0; r < 16; ++r) {
    int jl = r * 4 + jl0;
    float v = tile[jl][kl];
    US hv = f2bf(v);
    size_t o = (size_t)(j0 + jl) * 2048 + (size_t)(k0 + kl);
    t_hi[o] = hv;
    t_lo[o] = f2bf(v - bf2f(hv));
  }
}

// ---- build fragment-linear split weights W'[j'][k] -------------------------
// lin = ((jg*64+kc)*64+l)*8+e ; jg=j'>>4; kc=k>>5; l=((k>>3)&3)*16+(j'&15); e=k&7
__global__ __launch_bounds__(256) void build_wfrag(
    const float* __restrict__ src, US* __restrict__ t_hi, US* __restrict__ t_lo)
{
  __shared__ float tile[64][68];          // [j'local][k_local]
  const int ub = blockIdx.x >> 5;
  const int kb = blockIdx.x & 31;
  const int u0 = ub * 16, k0 = kb * 64;
  const int jg0 = ub * 4, kc0 = kb * 2;
  const int tid = threadIdx.x;

  const int g = tid >> 6, r2 = (tid >> 2) & 15, c4 = tid & 3;
  #pragma unroll
  for (int rr = 0; rr < 4; ++rr) {
    int row = rr * 16 + r2;
    size_t off = (size_t)(k0 + row) * 8192 + g * 2048 + u0 + c4 * 4;
    float4 v = *reinterpret_cast<const float4*>(src + off);
    tile[4 * (c4 * 4 + 0) + g][row] = v.x;
    tile[4 * (c4 * 4 + 1) + g][row] = v.y;
    tile[4 * (c4 * 4 + 2) + g][row] = v.z;
    tile[4 * (c4 * 4 + 3) + g][row] = v.w;
  }
  __syncthreads();

  #pragma unroll
  for (int it = 0; it < 2; ++it) {
    int idx = it * 256 + tid;
    int l = idx & 63, kcl = (idx >> 6) & 1, jgl = idx >> 7;
    int jloc = jgl * 16 + (l & 15);
    int kl = kcl * 32 + (l >> 4) * 8;
    float4 v0 = *reinterpret_cast<const float4*>(&tile[jloc][kl]);
    float4 v1 = *reinterpret_cast<const float4*>(&tile[jloc][kl + 4]);
    float f[8] = {v0.x, v0.y, v0.z, v0.w, v1.x, v1.y, v1.z, v1.w};
    unsigned int hp[4], lp[4];
    #pragma unroll
    for (int q = 0; q < 4; ++q) {
      US h0 = f2bf(f[2 * q]),     h1 = f2bf(f[2 * q + 1]);
      US s0 = f2bf(f[2 * q] - bf2f(h0));
      US s1 = f2bf(f[2 * q + 1] - bf2f(h1));
      hp[q] = (unsigned int)h0 | ((unsigned int)h1 << 16);
      lp[q] = (unsigned int)s0 | ((unsigned int)s1 << 16);
    }
    size_t base = (((size_t)(jg0 + jgl) * 64 + (kc0 + kcl)) * 64 + l) * 8;
    *reinterpret_cast<uint4*>(t_hi + base) = make_uint4(hp[0], hp[1], hp[2], hp[3]);
    *reinterpret_cast<uint4*>(t_lo + base) = make_uint4(lp[0], lp[1], lp[2], lp[3]);
  }
}

// ---- 128-row tiled GEMM, LDS-staged via global_load_lds, XOR swizzle -------
template<int NT, int EPI>
__global__ __launch_bounds__(256, 2) void gemm128(
    const US* __restrict__ Ah, const US* __restrict__ Al,
    const US* __restrict__ Bh, const US* __restrict__ Bl,
    const float* __restrict__ mproj,
    US* __restrict__ out0, US* __restrict__ out1,
    int MB, int ldo)
{
  constexpr int BN = NT * 32;
  __shared__ US sAh[128 * 64], sAl[128 * 64];
  __shared__ US sBh[BN * 64],  sBl[BN * 64];
  const int tid = threadIdx.x;
  const int w = tid >> 6, l = tid & 63;
  const int l16 = l & 15, lq = l >> 4;
  const int cpx = gridDim.x >> 3;
  const int swz = (blockIdx.x & 7) * cpx + (blockIdx.x >> 3);
  const int bm = swz % MB, bn = swz / MB;
  const int wm = w & 1, wn = w >> 1;
  const int AR0 = bm * 128, BR0 = bn * BN;

  f32x4 acc[4][NT];
  #pragma unroll
  for (int i = 0; i < 4; ++i)
    #pragma unroll
    for (int j = 0; j < NT; ++j) acc[i][j] = {0.f, 0.f, 0.f, 0.f};

  for (int k0 = 0; k0 < 2048; k0 += 64) {
    {
      #pragma unroll
      for (int i = 0; i < 4; ++i) {
        int c = (w * 4 + i) * 64 + l;
        int row = c >> 3, kc = c & 7;
        size_t go = (size_t)(AR0 + row) * 2048 + (k0 + ((kc ^ (row & 7)) << 3));
        gl_lds16(Ah + go, sAh + (w * 4 + i) * 512);
        gl_lds16(Al + go, sAl + (w * 4 + i) * 512);
      }
      constexpr int IPW = BN >> 5;
      #pragma unroll
      for (int i = 0; i < IPW; ++i) {
        int c = (w * IPW + i) * 64 + l;
        int row = c >> 3, kc = c & 7;
        size_t go = (size_t)(BR0 + row) * 2048 + (k0 + ((kc ^ (row & 7)) << 3));
        gl_lds16(Bh + go, sBh + (w * IPW + i) * 512);
        gl_lds16(Bl + go, sBl + (w * IPW + i) * 512);
      }
    }
    __syncthreads();
    #pragma unroll
    for (int ks = 0; ks < 2; ++ks) {
      const int kb = ks * 64 + lq * 16;
      bf16x8 ah[4], al[4], bh[NT], bl[NT];
      #pragma unroll
      for (int mt = 0; mt < 4; ++mt) {
        int r = wm * 64 + mt * 16 + l16;
        int off = r * 64 + ((kb ^ ((r & 7) << 4)) >> 1);
        ah[mt] = *reinterpret_cast<const bf16x8*>(sAh + off);
        al[mt] = *reinterpret_cast<const bf16x8*>(sAl + off);
      }
      #pragma unroll
      for (int nt = 0; nt < NT; ++nt) {
        int r = wn * (BN / 2) + nt * 16 + l16;
        int off = r * 64 + ((kb ^ ((r & 7) << 4)) >> 1);
        bh[nt] = *reinterpret_cast<const bf16x8*>(sBh + off);
        bl[nt] = *reinterpret_cast<const bf16x8*>(sBl + off);
      }
      #pragma unroll
      for (int mt = 0; mt < 4; ++mt)
        #pragma unroll
        for (int nt = 0; nt < NT; ++nt) {
          acc[mt][nt] = MFMA(ah[mt], bh[nt], acc[mt][nt]);
          acc[mt][nt] = MFMA(al[mt], bh[nt], acc[mt][nt]);
          acc[mt][nt] = MFMA(ah[mt], bl[nt], acc[mt][nt]);
        }
    }
    __syncthreads();
  }

  #pragma unroll
  for (int mt = 0; mt < 4; ++mt)
    #pragma unroll
    for (int nt = 0; nt < NT; ++nt) {
      int j = BR0 + wn * (BN / 2) + nt * 16 + l16;
      float mp = (EPI == 0) ? mproj[j] : 0.f;
      #pragma unroll
      for (int r = 0; r < 4; ++r) {
        int m = AR0 + wm * 64 + mt * 16 + lq * 4 + r;
        float v = acc[mt][nt][r] - mp;
        if constexpr (EPI == 0) {
          int t = m & 63, b = m >> 6;
          size_t o = (size_t)(t * 32 + b) * ldo + j;
          US hv = f2bf(v);
          out0[o] = hv;
          out1[o] = f2bf(v - bf2f(hv));
        } else {
          size_t o = (size_t)m * ldo + j;
          US hv = f2bf(v);
          out0[o] = hv;
          out1[o] = f2bf(v - bf2f(hv));
        }
      }
    }
}

// ---- fast device barrier: relaxed spin, single acquire fence (R7-proven) ---
__device__ __forceinline__ void gbar(int s, unsigned* bar)
{
  __syncthreads();
  if (threadIdx.x == 0) {
    __builtin_amdgcn_fence(__ATOMIC_RELEASE, "agent");
    const int g = blockIdx.x & 15;
    unsigned a = __hip_atomic_fetch_add(&bar[g * 16], 1u,
                    __ATOMIC_RELAXED, __HIP_MEMORY_SCOPE_AGENT);
    if (a == (unsigned)(16 * (s + 1) - 1)) {
      unsigned r = __hip_atomic_fetch_add(&bar[256], 1u,
                      __ATOMIC_RELAXED, __HIP_MEMORY_SCOPE_AGENT);
      if (r == (unsigned)(16 * (s + 1) - 1))
        __hip_atomic_store(&bar[272], (unsigned)(s + 1),
                           __ATOMIC_RELAXED, __HIP_MEMORY_SCOPE_AGENT);
    }
    while (__hip_atomic_load(&bar[272], __ATOMIC_RELAXED,
                             __HIP_MEMORY_SCOPE_AGENT) < (unsigned)(s + 1)) {
      __builtin_amdgcn_s_sleep(4);
    }
    __builtin_amdgcn_fence(__ATOMIC_ACQUIRE, "agent");
  }
  __syncthreads();
}

// ---- persistent LSTM: all 88 steps; W_hi in LDS, W_lo streamed -------------
// 256 blocks (block b owns units [8b,8b+8) = j' [32b,32b+32)), 512 thr = 8
// waves; wave kq covers kc in [8kq,8kq+8).
// LDS: WhL[2*64*64*8] bf16 (131072 B) + red[7][32][33] f32 (29568 B; zbuf
// [32][33] aliases red[0] -- wave-lockstep WAR-safe). Total 160640 B dynamic.
__global__ __launch_bounds__(512)
void lstm_persist(
    const US* __restrict__ rtf_hi, const US* __restrict__ rtf_lo,
    const float* __restrict__ Kmat,
    const US* __restrict__ zx_hi, const US* __restrict__ zx_lo,
    const float* __restrict__ bias,
    US* __restrict__ h_hi0, US* __restrict__ h_lo0,
    US* __restrict__ h_hi1, US* __restrict__ h_lo1,
    unsigned* __restrict__ bar, US* __restrict__ wl2,
    float* __restrict__ out)
{
  extern __shared__ char smem[];
  US* WhL = (US*)smem;                                   // 131072 B
  typedef float redrow[32][33];
  redrow* red = (redrow*)(smem + 131072);                // 7 slots, 29568 B
  float (*zb)[33] = (float(*)[33])(smem + 131072);       // aliases red[0]

  const int tid = threadIdx.x;
  const int kq = tid >> 6, l = tid & 63;
  const int b = blockIdx.x;
  const int l16 = l & 15, lq = l >> 4;

  // ---- load W_hi (R) into LDS, once, via global_load_lds ----
  #pragma unroll
  for (int jgl = 0; jgl < 2; ++jgl)
    #pragma unroll
    for (int kcl = 0; kcl < 8; ++kcl) {
      const int kc = kq * 8 + kcl;
      size_t go = (((size_t)(b * 2 + jgl) * 64 + kc) * 64 + l) * 8;
      gl_lds16(rtf_hi + go, WhL + ((jgl * 64 + kc) * 64) * 8);
    }

  // ---- cell-role constants (tid < 256: one (batch m, unit uu)) ----
  const int m = tid >> 3, uu = tid & 7;
  const int u = b * 8 + uu;
  float bz0 = 0.f, bz1 = 0.f, bz2 = 0.f, bz3 = 0.f, creg = 0.f;
  if (tid < 256) {
    bz0 = bias[u]; bz1 = bias[u + 2048];
    bz2 = bias[u + 4096]; bz3 = bias[u + 6144];
  }
  const int kcw = u >> 5, mhw = m >> 4;
  const int lw = ((u >> 3) & 3) * 16 + (m & 15);
  const size_t hwidx = (((size_t)kcw * 2 + mhw) * 64 + lw) * 8 + (u & 7);

  __syncthreads();    // W_hi staged (vmcnt drained by barrier)

  for (int s = 0; s < 88; ++s) {
    const int par = s & 1;
    const US* hfh = par ? h_hi1 : h_hi0;
    const US* hfl = par ? h_lo1 : h_lo0;
    US* hoh = par ? h_hi0 : h_hi1;
    US* hol = par ? h_lo0 : h_lo1;

    if (s == 64) {
      // transmute (block-local): LDS Wh := bf16(Wh+Wl+K); wl2 := residual
      #pragma unroll
      for (int jgl = 0; jgl < 2; ++jgl) {
        const int jp = (b * 2 + jgl) * 16 + l16;       // j' = 4u+g
        const int col = (jp & 3) * 2048 + (jp >> 2);   // source col g*2048+u
        #pragma unroll
        for (int kcl = 0; kcl < 8; ++kcl) {
          const int kc = kq * 8 + kcl;
          US* lp = WhL + ((jgl * 64 + kc) * 64 + l) * 8;
          size_t o = (((size_t)(b * 2 + jgl) * 64 + kc) * 64 + l) * 8;
          bf16x8 whr = *reinterpret_cast<const bf16x8*>(lp);
          bf16x8 wlr = *reinterpret_cast<const bf16x8*>(rtf_lo + o);
          const int k0 = kc * 32 + lq * 8;
          #pragma unroll
          for (int e = 0; e < 8; ++e) {
            float kv = Kmat[(size_t)(k0 + e) * 8192 + col];
            float wv = bf2f((US)whr[e]) + bf2f((US)wlr[e]) + kv;
            US hv = f2bf(wv);
            whr[e] = (short)hv;
            wlr[e] = (short)f2bf(wv - bf2f(hv));
          }
          *reinterpret_cast<bf16x8*>(lp) = whr;
          *reinterpret_cast<bf16x8*>(wl2 + o) = wlr;
        }
      }
      __syncthreads();   // LDS + wl2 stores visible block-wide
    }
    const US* wls = (s < 64) ? rtf_lo : (const US*)wl2;

    // ---- partial z: wave kq covers k in [kq*256, kq*256+256) ----
    f32x4 acc00 = {0.f,0.f,0.f,0.f}, acc01 = {0.f,0.f,0.f,0.f};
    f32x4 acc10 = {0.f,0.f,0.f,0.f}, acc11 = {0.f,0.f,0.f,0.f};
    #pragma unroll
    for (int kcl = 0; kcl < 8; ++kcl) {
      const int kc = kq * 8 + kcl;
      const US* ah = hfh + ((size_t)kc * 2 * 64 + l) * 8;
      const US* al = hfl + ((size_t)kc * 2 * 64 + l) * 8;
      bf16x8 a0h = *reinterpret_cast<const bf16x8*>(ah);
      bf16x8 a1h = *reinterpret_cast<const bf16x8*>(ah + 512);
      bf16x8 a0l = *reinterpret_cast<const bf16x8*>(al);
      bf16x8 a1l = *reinterpret_cast<const bf16x8*>(al + 512);
      bf16x8 wh0 = *reinterpret_cast<const bf16x8*>(WhL + ((0 * 64 + kc) * 64 + l) * 8);
      bf16x8 wh1 = *reinterpret_cast<const bf16x8*>(WhL + ((1 * 64 + kc) * 64 + l) * 8);
      size_t o0 = (((size_t)(b * 2 + 0) * 64 + kc) * 64 + l) * 8;
      size_t o1 = (((size_t)(b * 2 + 1) * 64 + kc) * 64 + l) * 8;
      bf16x8 wl0 = *reinterpret_cast<const bf16x8*>(wls + o0);
      bf16x8 wl1 = *reinterpret_cast<const bf16x8*>(wls + o1);
      acc00 = MFMA(a0h, wh0, acc00);
      acc01 = MFMA(a0h, wh1, acc01);
      acc10 = MFMA(a1h, wh0, acc10);
      acc11 = MFMA(a1h, wh1, acc11);
      acc00 = MFMA(a0l, wh0, acc00);
      acc01 = MFMA(a0l, wh1, acc01);
      acc10 = MFMA(a1l, wh0, acc10);
      acc11 = MFMA(a1l, wh1, acc11);
      acc00 = MFMA(a0h, wl0, acc00);
      acc01 = MFMA(a0h, wl1, acc01);
      acc10 = MFMA(a1h, wl0, acc10);
      acc11 = MFMA(a1h, wl1, acc11);
    }

    // ---- reduce: waves 1..7 write partials; wave 0 accumulates ----
    if (kq > 0) {
      #pragma unroll
      for (int r = 0; r < 4; ++r) {
        red[kq - 1][l16][lq * 4 + r]           = acc00[r];
        red[kq - 1][16 + l16][lq * 4 + r]      = acc01[r];
        red[kq - 1][l16][16 + lq * 4 + r]      = acc10[r];
        red[kq - 1][16 + l16][16 + lq * 4 + r] = acc11[r];
      }
    }
    __syncthreads();
    if (kq == 0) {
      #pragma unroll
      for (int q = 0; q < 7; ++q)
        #pragma unroll
        for (int r = 0; r < 4; ++r) {
          acc00[r] += red[q][l16][lq * 4 + r];
          acc01[r] += red[q][16 + l16][lq * 4 + r];
          acc10[r] += red[q][l16][16 + lq * 4 + r];
          acc11[r] += red[q][16 + l16][16 + lq * 4 + r];
        }
      // write z tile (zb aliases red[0]; wave-lockstep => reads precede writes)
      #pragma unroll
      for (int r = 0; r < 4; ++r) {
        zb[l16][lq * 4 + r]           = acc00[r];
        zb[16 + l16][lq * 4 + r]      = acc01[r];
        zb[l16][16 + lq * 4 + r]      = acc10[r];
        zb[16 + l16][16 + lq * 4 + r] = acc11[r];
      }
    }
    __syncthreads();

    if (tid < 256) {
      float z0 = bz0 + zb[uu * 4 + 0][m];
      float z1 = bz1 + zb[uu * 4 + 1][m];
      float z2 = bz2 + zb[uu * 4 + 2][m];
      float z3 = bz3 + zb[uu * 4 + 3][m];
      if (s < 64) {
        size_t zo = (size_t)(s * 32 + m) * 8192 + (size_t)u * 4;
        z0 += bf2f(zx_hi[zo + 0]) + bf2f(zx_lo[zo + 0]);
        z1 += bf2f(zx_hi[zo + 1]) + bf2f(zx_lo[zo + 1]);
        z2 += bf2f(zx_hi[zo + 2]) + bf2f(zx_lo[zo + 2]);
        z3 += bf2f(zx_hi[zo + 3]) + bf2f(zx_lo[zo + 3]);
      }
      float gi = 1.f / (1.f + expf(-z0));
      float gf = 1.f / (1.f + expf(-z1));
      float gg = tanhf(z2);
      float go = 1.f / (1.f + expf(-z3));
      creg = gf * creg + gi * gg;
      float hn = go * tanhf(creg);
      US hv = f2bf(hn);
      hoh[hwidx] = hv;
      hol[hwidx] = f2bf(hn - bf2f(hv));
      if (s >= 64) out[((size_t)m * 24 + (s - 64)) * 2048 + u] = hn;
    }
    gbar(s, bar);
  }
}

// ============================================================================
extern "C" void kernel_launch(void* const* d_in, const int* in_sizes, int n_in,
                              void* d_out, int out_size, void* d_ws, size_t ws_size,
                              hipStream_t stream)
{
  const float* inputs = (const float*)d_in[0];   // (32,64,2048,1)
  const float* comp   = (const float*)d_in[1];   // (2048,2048)
  const float* mean   = (const float*)d_in[2];   // (2048,)
  const float* Kmat   = (const float*)d_in[3];   // (2048,8192)
  const float* Rmat   = (const float*)d_in[4];   // (2048,8192)
  const float* bias   = (const float*)d_in[5];   // (8192,)
  float* out = (float*)d_out;                    // (32,24,2048)

  // ---- workspace layout (177 MiB envelope, proven in R1-R8) ----
  const size_t MiB = 1024 * 1024;
  char* base = (char*)d_ws;
  US* zx_hi   = (US*)(base);                     // [0,32)   2048x8192 bf16
  US* zx_lo   = (US*)(base + 32 * MiB);          // [32,64)
  US* KT_hi   = (US*)(base + 64 * MiB);          // [64,96)  row-major K^T
  US* KT_lo   = (US*)(base + 96 * MiB);          // [96,128)
  US* RTf_hi  = KT_hi;                           // over dead KT (after zx gemm)
  US* RTf_lo  = KT_lo;
  US* flat_hi = (US*)(base + 128 * MiB);         // [128,136)
  US* flat_lo = (US*)(base + 136 * MiB);         // [136,144)
  US* comp_hi = (US*)(base + 144 * MiB);         // [144,152)
  US* comp_lo = (US*)(base + 152 * MiB);         // [152,160)
  US* wl2     = (US*)(base + 128 * MiB);         // decoder W_lo (over dead flat/comp)
  US* xs_hi   = (US*)(base + 160 * MiB);         // [160,168)
  US* xs_lo   = (US*)(base + 168 * MiB);         // [168,176)
  char* Mz = base + 176 * MiB;
  float* mproj = (float*)(Mz);
  US* hh0 = (US*)(Mz + 64 * 1024);
  US* hl0 = (US*)(Mz + 256 * 1024);
  US* hh1 = (US*)(Mz + 448 * 1024);
  US* hl1 = (US*)(Mz + 640 * 1024);
  unsigned* bar = (unsigned*)(Mz + 832 * 1024);  // 4 KiB barrier state

  // ---- prep ----
  split_kernel<<<4096, 256, 0, stream>>>(inputs, flat_hi, flat_lo, 1048576);
  split_kernel<<<4096, 256, 0, stream>>>(comp,   comp_hi, comp_lo, 1048576);
  mproj_kernel<<<2048, 256, 0, stream>>>(mean, comp, mproj);
  build_kt<<<4096, 256, 0, stream>>>(Kmat, KT_hi, KT_lo);
  zero_kernel<<<256, 256, 0, stream>>>(hh0, hl0, bar);

  // xs = (flat - mean) @ comp^T  (2048 x 2048), rows remapped to t*32+b
  gemm128<2, 0><<<512, 256, 0, stream>>>(flat_hi, flat_lo, comp_hi, comp_lo,
                                         mproj, xs_hi, xs_lo, 16, 2048);
  // zx = xs @ K^T  (2048 x 8192, gate-interleaved cols), bf16 hi/lo store
  gemm128<4, 2><<<1024, 256, 0, stream>>>(xs_hi, xs_lo, KT_hi, KT_lo,
                                          nullptr, zx_hi, zx_lo, 16, 8192);
  // RTf (fragment-linear R^T) over the now-dead KT region
  build_wfrag<<<4096, 256, 0, stream>>>(Rmat, RTf_hi, RTf_lo);

  // ---- all 88 steps in one persistent kernel (coop launch, 160 KiB LDS) ----
  const size_t LDS_BYTES = 131072 + 7 * 32 * 33 * 4;   // 160640
  (void)hipFuncSetAttribute((const void*)lstm_persist,
                            hipFuncAttributeMaxDynamicSharedMemorySize,
                            (int)LDS_BYTES);
  const US* a_rtf_hi = RTf_hi; const US* a_rtf_lo = RTf_lo;
  const float* a_kmat = Kmat;
  const US* a_zx_hi = zx_hi;   const US* a_zx_lo = zx_lo;
  const float* a_bias = bias;
  US* a_hh0 = hh0; US* a_hl0 = hl0; US* a_hh1 = hh1; US* a_hl1 = hl1;
  unsigned* a_bar = bar;       US* a_wl2 = wl2;
  float* a_out = out;
  void* args[] = {
    (void*)&a_rtf_hi, (void*)&a_rtf_lo, (void*)&a_kmat,
    (void*)&a_zx_hi, (void*)&a_zx_lo, (void*)&a_bias,
    (void*)&a_hh0, (void*)&a_hl0, (void*)&a_hh1, (void*)&a_hl1,
    (void*)&a_bar, (void*)&a_wl2, (void*)&a_out
  };
  hipLaunchCooperativeKernel((void*)lstm_persist, dim3(256), dim3(512),
                             args, (unsigned)LDS_BYTES, stream);
}

// Round 10
// 1274.706 us; speedup vs baseline: 1.7251x; 1.7251x over previous
//
#include <hip/hip_runtime.h>
#include <math.h>

// ============================================================================
// PCA + LSTM encoder/decoder on MI355X.  (R10: back to the proven R3
// multi-dispatch structure; fp16 2-term replaces bf16 3-term everywhere.)
//  - z = a_hi*W + a_lo*W : activations exact (fp16 hi+lo), weights single
//    fp16 (2^-12) -> HALF the weight stream (32 MiB/step), 2 MFMAs per tile.
//  - Encoder x@K precomputed for all 64 steps in ONE GEMM (zx, fp32).
//  - Decoder x == h  =>  z = h @ (K+R) (summed fp32 then fp16).
//  - lstm_step: fragment-linear weights -> every load is a coalesced 1KB
//    wave load direct to VGPRs (R3-proven, ~4 TB/s effective = fabric rate).
// ============================================================================

typedef unsigned short US;
typedef __attribute__((ext_vector_type(8))) _Float16 f16x8;
typedef __attribute__((ext_vector_type(4))) float f32x4;

typedef __attribute__((address_space(3))) unsigned int as3_uint;
typedef __attribute__((address_space(1))) unsigned int as1_uint;

#define MFMA16(a, b, c) __builtin_amdgcn_mfma_f32_16x16x32_f16(a, b, c, 0, 0, 0)

__device__ __forceinline__ US f2h(float x) {      // RNE fp32 -> fp16 bits
  _Float16 h = (_Float16)x;
  return __builtin_bit_cast(US, h);
}
__device__ __forceinline__ float h2f(US u) {
  return (float)__builtin_bit_cast(_Float16, u);
}

__device__ __forceinline__ void gl_lds16(const US* g, US* l) {
  __builtin_amdgcn_global_load_lds((const as1_uint*)g, (as3_uint*)l, 16, 0, 0);
}

// ---- fp32 -> fp16 hi/lo split ----------------------------------------------
__global__ __launch_bounds__(256) void split16_kernel(
    const float* __restrict__ in, US* __restrict__ hi, US* __restrict__ lo, int n4)
{
  int i = blockIdx.x * 256 + threadIdx.x;
  if (i >= n4) return;
  float4 v = reinterpret_cast<const float4*>(in)[i];
  US h0 = f2h(v.x), h1 = f2h(v.y), h2 = f2h(v.z), h3 = f2h(v.w);
  reinterpret_cast<ushort4*>(hi)[i] = make_ushort4(h0, h1, h2, h3);
  reinterpret_cast<ushort4*>(lo)[i] =
      make_ushort4(f2h(v.x - h2f(h0)), f2h(v.y - h2f(h1)),
                   f2h(v.z - h2f(h2)), f2h(v.w - h2f(h3)));
}

// ---- fp32 -> fp16 (single) --------------------------------------------------
__global__ __launch_bounds__(256) void cvt16_kernel(
    const float* __restrict__ in, US* __restrict__ o16, int n4)
{
  int i = blockIdx.x * 256 + threadIdx.x;
  if (i >= n4) return;
  float4 v = reinterpret_cast<const float4*>(in)[i];
  reinterpret_cast<ushort4*>(o16)[i] =
      make_ushort4(f2h(v.x), f2h(v.y), f2h(v.z), f2h(v.w));
}

// ---- zero c (fp32) and initial h hi/lo (fp16) -------------------------------
__global__ void zero_kernel(float* __restrict__ c, US* __restrict__ h0,
                            US* __restrict__ l0)
{
  int i = blockIdx.x * 256 + threadIdx.x;   // grid covers 65536 exactly
  c[i] = 0.f; h0[i] = 0; l0[i] = 0;
}

// ---- mproj[j] = sum_k mean[k] * comp[j][k]  (fp32) --------------------------
__global__ __launch_bounds__(256) void mproj_kernel(
    const float* __restrict__ mean, const float* __restrict__ comp,
    float* __restrict__ mproj)
{
  int j = blockIdx.x;
  const float* row = comp + (size_t)j * 2048;
  float s = 0.f;
  for (int k = threadIdx.x; k < 2048; k += 256) s += mean[k] * row[k];
  __shared__ float ss[4];
  #pragma unroll
  for (int o = 32; o > 0; o >>= 1) s += __shfl_down(s, o, 64);
  if ((threadIdx.x & 63) == 0) ss[threadIdx.x >> 6] = s;
  __syncthreads();
  if (threadIdx.x == 0) mproj[j] = ss[0] + ss[1] + ss[2] + ss[3];
}

// ---- build KT[j'][k] row-major gate-interleaved transpose, fp16 -------------
// j' = 4*u + g  <->  source col g*2048+u.
__global__ __launch_bounds__(256) void build_kt16(
    const float* __restrict__ src, US* __restrict__ t16)
{
  __shared__ float tile[64][65];
  const int jblk = blockIdx.x >> 5;       // 0..127
  const int kblk = blockIdx.x & 31;       // 0..31
  const int j0 = jblk * 64;
  const int u0 = j0 >> 2;
  const int k0 = kblk * 64;
  const int tid = threadIdx.x;
  const int cc = tid & 63;
  const int g = cc >> 4, uo = cc & 15;
  const int col = g * 2048 + u0 + uo;
  const int kl0 = tid >> 6;
  #pragma unroll
  for (int r = 0; r < 16; ++r) {
    int kl = r * 4 + kl0;
    tile[4 * uo + g][kl] = src[(size_t)(k0 + kl) * 8192 + col];
  }
  __syncthreads();
  const int kl = tid & 63;
  const int jl0 = tid >> 6;
  #pragma unroll
  for (int r = 0; r < 16; ++r) {
    int jl = r * 4 + jl0;
    t16[(size_t)(j0 + jl) * 2048 + (size_t)(k0 + kl)] = f2h(tile[jl][kl]);
  }
}

// ---- build fragment-linear fp16 weights W'[j'][k] ---------------------------
// lin = ((jg*64+kc)*64+l)*8+e ; jg=j'>>4; kc=k>>5; l=((k>>3)&3)*16+(j'&15); e=k&7
// SUM: srcA + srcB (fp32 sum, then fp16) for the decoder K+R.
template<bool SUM>
__global__ __launch_bounds__(256) void build_wfrag16(
    const float* __restrict__ srcA, const float* __restrict__ srcB,
    US* __restrict__ t16)
{
  __shared__ float tile[64][68];          // [j'local][k_local]
  const int ub = blockIdx.x >> 5;         // 0..127 (16 units each)
  const int kb = blockIdx.x & 31;         // 0..31  (64 k each)
  const int u0 = ub * 16, k0 = kb * 64;
  const int jg0 = ub * 4, kc0 = kb * 2;
  const int tid = threadIdx.x;

  const int g = tid >> 6, r2 = (tid >> 2) & 15, c4 = tid & 3;
  #pragma unroll
  for (int rr = 0; rr < 4; ++rr) {
    int row = rr * 16 + r2;
    size_t off = (size_t)(k0 + row) * 8192 + g * 2048 + u0 + c4 * 4;
    float4 v = *reinterpret_cast<const float4*>(srcA + off);
    if (SUM) {
      float4 w = *reinterpret_cast<const float4*>(srcB + off);
      v.x += w.x; v.y += w.y; v.z += w.z; v.w += w.w;
    }
    tile[4 * (c4 * 4 + 0) + g][row] = v.x;
    tile[4 * (c4 * 4 + 1) + g][row] = v.y;
    tile[4 * (c4 * 4 + 2) + g][row] = v.z;
    tile[4 * (c4 * 4 + 3) + g][row] = v.w;
  }
  __syncthreads();

  #pragma unroll
  for (int it = 0; it < 2; ++it) {
    int idx = it * 256 + tid;
    int l = idx & 63, kcl = (idx >> 6) & 1, jgl = idx >> 7;
    int jloc = jgl * 16 + (l & 15);
    int kl = kcl * 32 + (l >> 4) * 8;
    float4 v0 = *reinterpret_cast<const float4*>(&tile[jloc][kl]);
    float4 v1 = *reinterpret_cast<const float4*>(&tile[jloc][kl + 4]);
    float f[8] = {v0.x, v0.y, v0.z, v0.w, v1.x, v1.y, v1.z, v1.w};
    unsigned int hp[4];
    #pragma unroll
    for (int q = 0; q < 4; ++q)
      hp[q] = (unsigned int)f2h(f[2 * q]) | ((unsigned int)f2h(f[2 * q + 1]) << 16);
    size_t base = (((size_t)(jg0 + jgl) * 64 + (kc0 + kcl)) * 64 + l) * 8;
    *reinterpret_cast<uint4*>(t16 + base) = make_uint4(hp[0], hp[1], hp[2], hp[3]);
  }
}

// ---- 128-row tiled GEMM, fp16 2-term: C = (Ah+Al) @ B^T ---------------------
// LDS-staged via global_load_lds + XOR swizzle + XCD block swizzle.
// EPI 0: pca (sub mproj, row remap b*64+t -> t*32+b, fp16 hi/lo split store)
// EPI 1: plain fp32 store.
template<int NT, int EPI>
__global__ __launch_bounds__(256, 2) void gemm128h(
    const US* __restrict__ Ah, const US* __restrict__ Al,
    const US* __restrict__ B, const float* __restrict__ mproj,
    US* __restrict__ out0, US* __restrict__ out1,
    int MB, int ldo)
{
  constexpr int BN = NT * 32;
  __shared__ US sAh[128 * 64], sAl[128 * 64];
  __shared__ US sB[BN * 64];
  const int tid = threadIdx.x;
  const int w = tid >> 6, l = tid & 63;
  const int l16 = l & 15, lq = l >> 4;
  const int cpx = gridDim.x >> 3;
  const int swz = (blockIdx.x & 7) * cpx + (blockIdx.x >> 3);
  const int bm = swz % MB, bn = swz / MB;
  const int wm = w & 1, wn = w >> 1;
  const int AR0 = bm * 128, BR0 = bn * BN;

  f32x4 acc[4][NT];
  #pragma unroll
  for (int i = 0; i < 4; ++i)
    #pragma unroll
    for (int j = 0; j < NT; ++j) acc[i][j] = {0.f, 0.f, 0.f, 0.f};

  for (int k0 = 0; k0 < 2048; k0 += 64) {
    {
      #pragma unroll
      for (int i = 0; i < 4; ++i) {          // A tiles: 128 rows, hi+lo
        int c = (w * 4 + i) * 64 + l;
        int row = c >> 3, kc = c & 7;
        size_t go = (size_t)(AR0 + row) * 2048 + (k0 + ((kc ^ (row & 7)) << 3));
        gl_lds16(Ah + go, sAh + (w * 4 + i) * 512);
        gl_lds16(Al + go, sAl + (w * 4 + i) * 512);
      }
      constexpr int IPW = BN >> 5;           // B tiles: BN rows
      #pragma unroll
      for (int i = 0; i < IPW; ++i) {
        int c = (w * IPW + i) * 64 + l;
        int row = c >> 3, kc = c & 7;
        size_t go = (size_t)(BR0 + row) * 2048 + (k0 + ((kc ^ (row & 7)) << 3));
        gl_lds16(B + go, sB + (w * IPW + i) * 512);
      }
    }
    __syncthreads();
    #pragma unroll
    for (int ks = 0; ks < 2; ++ks) {
      const int kb = ks * 64 + lq * 16;
      f16x8 ah[4], al[4], bb[NT];
      #pragma unroll
      for (int mt = 0; mt < 4; ++mt) {
        int r = wm * 64 + mt * 16 + l16;
        int off = r * 64 + ((kb ^ ((r & 7) << 4)) >> 1);
        ah[mt] = *reinterpret_cast<const f16x8*>(sAh + off);
        al[mt] = *reinterpret_cast<const f16x8*>(sAl + off);
      }
      #pragma unroll
      for (int nt = 0; nt < NT; ++nt) {
        int r = wn * (BN / 2) + nt * 16 + l16;
        int off = r * 64 + ((kb ^ ((r & 7) << 4)) >> 1);
        bb[nt] = *reinterpret_cast<const f16x8*>(sB + off);
      }
      #pragma unroll
      for (int mt = 0; mt < 4; ++mt)
        #pragma unroll
        for (int nt = 0; nt < NT; ++nt) {
          acc[mt][nt] = MFMA16(ah[mt], bb[nt], acc[mt][nt]);
          acc[mt][nt] = MFMA16(al[mt], bb[nt], acc[mt][nt]);
        }
    }
    __syncthreads();
  }

  #pragma unroll
  for (int mt = 0; mt < 4; ++mt)
    #pragma unroll
    for (int nt = 0; nt < NT; ++nt) {
      int j = BR0 + wn * (BN / 2) + nt * 16 + l16;
      float mp = (EPI == 0) ? mproj[j] : 0.f;
      #pragma unroll
      for (int r = 0; r < 4; ++r) {
        int m = AR0 + wm * 64 + mt * 16 + lq * 4 + r;
        float v = acc[mt][nt][r] - mp;
        if constexpr (EPI == 0) {
          int t = m & 63, b = m >> 6;
          size_t o = (size_t)(t * 32 + b) * ldo + j;
          US hv = f2h(v);
          out0[o] = hv;
          out1[o] = f2h(v - h2f(hv));
        } else {
          ((float*)out0)[(size_t)m * ldo + j] = v;
        }
      }
    }
}

// ---- one LSTM step: z = zx + (h_hi + h_lo) @ W'^T + bias ; fused cell ------
// Fragment-linear fp16 W: every weight load is a coalesced 1KB wave load.
// grid 512 blocks (jg: 16 j' = 4 units), 512 thr = 8 waves = 8-way split-K.
__global__ __launch_bounds__(512, 4) void lstm_step16(
    const US* __restrict__ hf_hi, const US* __restrict__ hf_lo,   // frag (32,2048)
    const US* __restrict__ wf,                                    // frag (8192,2048)
    const float* __restrict__ zx,                                 // (32,8192) or null
    const float* __restrict__ bias, float* __restrict__ cst,
    US* __restrict__ ho_hi, US* __restrict__ ho_lo,               // frag (32,2048)
    float* __restrict__ pred, int p)
{
  __shared__ float red[7][64][9];
  __shared__ float zbuf[32][17];
  const int tid = threadIdx.x;
  const int kq = tid >> 6, l = tid & 63;
  const int jg = blockIdx.x;
  const int l16 = l & 15, lq = l >> 4;

  const US* wp = wf    + (((size_t)jg * 64 + kq * 8) * 64 + l) * 8;
  const US* ah = hf_hi + (((size_t)kq * 16) * 64 + l) * 8;
  const US* al = hf_lo + (((size_t)kq * 16) * 64 + l) * 8;

  f32x4 acc0 = {0.f,0.f,0.f,0.f}, acc1 = {0.f,0.f,0.f,0.f};
  #pragma unroll
  for (int c = 0; c < 8; ++c) {
    f16x8 wv  = *reinterpret_cast<const f16x8*>(wp + c * 512);
    f16x8 a0h = *reinterpret_cast<const f16x8*>(ah + c * 1024);
    f16x8 a1h = *reinterpret_cast<const f16x8*>(ah + c * 1024 + 512);
    f16x8 a0l = *reinterpret_cast<const f16x8*>(al + c * 1024);
    f16x8 a1l = *reinterpret_cast<const f16x8*>(al + c * 1024 + 512);
    acc0 = MFMA16(a0h, wv, acc0);
    acc1 = MFMA16(a1h, wv, acc1);
    acc0 = MFMA16(a0l, wv, acc0);
    acc1 = MFMA16(a1l, wv, acc1);
  }

  if (kq > 0) {
    #pragma unroll
    for (int r = 0; r < 4; ++r) {
      red[kq - 1][l][r]     = acc0[r];
      red[kq - 1][l][r + 4] = acc1[r];
    }
  }
  __syncthreads();
  if (kq == 0) {
    #pragma unroll
    for (int q = 0; q < 7; ++q)
      #pragma unroll
      for (int r = 0; r < 4; ++r) {
        acc0[r] += red[q][l][r];
        acc1[r] += red[q][l][r + 4];
      }
    #pragma unroll
    for (int r = 0; r < 4; ++r) {
      zbuf[lq * 4 + r][l16]      = acc0[r];
      zbuf[lq * 4 + r + 16][l16] = acc1[r];
    }
  }
  __syncthreads();

  if (tid < 128) {
    int m = tid >> 2, ul = tid & 3;
    int u = jg * 4 + ul;
    float zi = zbuf[m][ul * 4 + 0] + bias[u];
    float zf = zbuf[m][ul * 4 + 1] + bias[u + 2048];
    float zg = zbuf[m][ul * 4 + 2] + bias[u + 4096];
    float zo = zbuf[m][ul * 4 + 3] + bias[u + 6144];
    if (zx) {
      const float* zr = zx + (size_t)m * 8192 + (size_t)u * 4;
      zi += zr[0]; zf += zr[1]; zg += zr[2]; zo += zr[3];
    }
    float gi = 1.f / (1.f + expf(-zi));
    float gf = 1.f / (1.f + expf(-zf));
    float gg = tanhf(zg);
    float go = 1.f / (1.f + expf(-zo));
    float cn = gf * cst[m * 2048 + u] + gi * gg;
    float hn = go * tanhf(cn);
    cst[m * 2048 + u] = cn;
    // h write in fragment-linear layout for next step's A loads
    int kc = u >> 5, mh = m >> 4;
    int lw = ((u >> 3) & 3) * 16 + (m & 15);
    int e = u & 7;
    size_t hidx = (((size_t)kc * 2 + mh) * 64 + lw) * 8 + e;
    US hh = f2h(hn);
    ho_hi[hidx] = hh;
    ho_lo[hidx] = f2h(hn - h2f(hh));
    if (p >= 0) pred[(size_t)(m * 24 + p) * 2048 + u] = hn;
  }
}

// ============================================================================
extern "C" void kernel_launch(void* const* d_in, const int* in_sizes, int n_in,
                              void* d_out, int out_size, void* d_ws, size_t ws_size,
                              hipStream_t stream)
{
  const float* inputs = (const float*)d_in[0];   // (32,64,2048,1)
  const float* comp   = (const float*)d_in[1];   // (2048,2048)
  const float* mean   = (const float*)d_in[2];   // (2048,)
  const float* Kmat   = (const float*)d_in[3];   // (2048,8192)
  const float* Rmat   = (const float*)d_in[4];   // (2048,8192)
  const float* bias   = (const float*)d_in[5];   // (8192,)
  float* out = (float*)d_out;                    // (32,24,2048)

  // ---- workspace layout (169 MiB, within the proven 177 MiB envelope) ----
  const size_t MiB = 1024 * 1024;
  char* base = (char*)d_ws;
  float* zx    = (float*)(base);                 // [0,64)   fp32 2048x8192
  US* KT       = (US*)(base + 64 * MiB);         // [64,96)  row-major K^T fp16
  US* WSTf     = KT;                             // frag (K+R), over dead KT
  US* RTf      = (US*)(base + 96 * MiB);         // [96,128) frag R fp16
  US* flat_hi  = (US*)(base + 128 * MiB);        // [128,136)
  US* flat_lo  = (US*)(base + 136 * MiB);        // [136,144)
  US* comp16   = (US*)(base + 144 * MiB);        // [144,152)
  US* xs_hi    = (US*)(base + 152 * MiB);        // [152,160)
  US* xs_lo    = (US*)(base + 160 * MiB);        // [160,168)
  char* Mz = base + 168 * MiB;
  float* mproj = (float*)(Mz);                   // 8 KB
  float* cbuf  = (float*)(Mz + 64 * 1024);       // 256 KB fp32 c-state
  US* hh[2]; US* hl[2];
  hh[0] = (US*)(Mz + 320 * 1024);
  hl[0] = (US*)(Mz + 448 * 1024);
  hh[1] = (US*)(Mz + 576 * 1024);
  hl[1] = (US*)(Mz + 704 * 1024);

  // ---- prep ----
  split16_kernel<<<4096, 256, 0, stream>>>(inputs, flat_hi, flat_lo, 1048576);
  cvt16_kernel<<<4096, 256, 0, stream>>>(comp, comp16, 1048576);
  mproj_kernel<<<2048, 256, 0, stream>>>(mean, comp, mproj);
  build_kt16<<<4096, 256, 0, stream>>>(Kmat, KT);
  zero_kernel<<<256, 256, 0, stream>>>(cbuf, hh[0], hl[0]);

  // xs = (flat - mean) @ comp^T  (2048 x 2048), rows remapped to t*32+b
  gemm128h<2, 0><<<512, 256, 0, stream>>>(flat_hi, flat_lo, comp16,
                                          mproj, xs_hi, xs_lo, 16, 2048);
  // zx = xs @ K^T  (2048 x 8192, gate-interleaved cols), fp32 store
  gemm128h<4, 1><<<1024, 256, 0, stream>>>(xs_hi, xs_lo, KT,
                                           nullptr, (US*)zx, nullptr, 16, 8192);
  // fragment-linear weights: R (encoder); K+R (decoder) over the dead KT
  build_wfrag16<false><<<4096, 256, 0, stream>>>(Rmat, nullptr, RTf);
  build_wfrag16<true><<<4096, 256, 0, stream>>>(Kmat, Rmat, WSTf);

  // ---- 64 encoder steps: z = zx[s] + h @ R^T ----
  for (int s = 0; s < 64; ++s) {
    int par = s & 1;
    lstm_step16<<<512, 512, 0, stream>>>(hh[par], hl[par], RTf,
                                         zx + (size_t)s * 32 * 8192,
                                         bias, cbuf, hh[1 - par], hl[1 - par],
                                         out, -1);
  }
  // ---- 24 decoder steps: z = h @ (K+R)^T ----
  for (int s = 64; s < 88; ++s) {
    int par = s & 1;
    lstm_step16<<<512, 512, 0, stream>>>(hh[par], hl[par], WSTf,
                                         nullptr,
                                         bias, cbuf, hh[1 - par], hl[1 - par],
                                         out, s - 64);
  }
}

// Round 11
// 1053.267 us; speedup vs baseline: 2.0878x; 1.2102x over previous
//
#include <hip/hip_runtime.h>
#include <math.h>

// ============================================================================
// PCA + LSTM encoder/decoder on MI355X.  (R11 = R10 structure, fixed-cost cuts)
//  - Weights: single fp16, fragment-linear (32 MiB/step stream @ ~HBM BW).
//  - h: SINGLE fp16 term (R10's h_lo dropped -- error ~1e-4/step, invisible
//    under the 3.9e-3 fp16-W floor). Halves h traffic and step MFMA count.
//  - zx: fp16 (halves zx GEMM write + per-step read).
//  - RTf + WSTf built in ONE pass over Kmat+Rmat.
//  - Encoder x@K precomputed in ONE GEMM; decoder uses K+R summed.
// ============================================================================

typedef unsigned short US;
typedef __attribute__((ext_vector_type(8))) _Float16 f16x8;
typedef __attribute__((ext_vector_type(4))) float f32x4;

typedef __attribute__((address_space(3))) unsigned int as3_uint;
typedef __attribute__((address_space(1))) unsigned int as1_uint;

#define MFMA16(a, b, c) __builtin_amdgcn_mfma_f32_16x16x32_f16(a, b, c, 0, 0, 0)

__device__ __forceinline__ US f2h(float x) {      // RNE fp32 -> fp16 bits
  _Float16 h = (_Float16)x;
  return __builtin_bit_cast(US, h);
}
__device__ __forceinline__ float h2f(US u) {
  return (float)__builtin_bit_cast(_Float16, u);
}

__device__ __forceinline__ void gl_lds16(const US* g, US* l) {
  __builtin_amdgcn_global_load_lds((const as1_uint*)g, (as3_uint*)l, 16, 0, 0);
}

// ---- fp32 -> fp16 hi/lo split (PCA A operand keeps 2-term accuracy) ---------
__global__ __launch_bounds__(256) void split16_kernel(
    const float* __restrict__ in, US* __restrict__ hi, US* __restrict__ lo, int n4)
{
  int i = blockIdx.x * 256 + threadIdx.x;
  if (i >= n4) return;
  float4 v = reinterpret_cast<const float4*>(in)[i];
  US h0 = f2h(v.x), h1 = f2h(v.y), h2 = f2h(v.z), h3 = f2h(v.w);
  reinterpret_cast<ushort4*>(hi)[i] = make_ushort4(h0, h1, h2, h3);
  reinterpret_cast<ushort4*>(lo)[i] =
      make_ushort4(f2h(v.x - h2f(h0)), f2h(v.y - h2f(h1)),
                   f2h(v.z - h2f(h2)), f2h(v.w - h2f(h3)));
}

// ---- fp32 -> fp16 (single) --------------------------------------------------
__global__ __launch_bounds__(256) void cvt16_kernel(
    const float* __restrict__ in, US* __restrict__ o16, int n4)
{
  int i = blockIdx.x * 256 + threadIdx.x;
  if (i >= n4) return;
  float4 v = reinterpret_cast<const float4*>(in)[i];
  reinterpret_cast<ushort4*>(o16)[i] =
      make_ushort4(f2h(v.x), f2h(v.y), f2h(v.z), f2h(v.w));
}

// ---- zero c (fp32) and initial h (fp16) -------------------------------------
__global__ void zero_kernel(float* __restrict__ c, US* __restrict__ h0)
{
  int i = blockIdx.x * 256 + threadIdx.x;   // grid covers 65536 exactly
  c[i] = 0.f; h0[i] = 0;
}

// ---- mproj[j] = sum_k mean[k] * comp[j][k]  (fp32) --------------------------
__global__ __launch_bounds__(256) void mproj_kernel(
    const float* __restrict__ mean, const float* __restrict__ comp,
    float* __restrict__ mproj)
{
  int j = blockIdx.x;
  const float* row = comp + (size_t)j * 2048;
  float s = 0.f;
  for (int k = threadIdx.x; k < 2048; k += 256) s += mean[k] * row[k];
  __shared__ float ss[4];
  #pragma unroll
  for (int o = 32; o > 0; o >>= 1) s += __shfl_down(s, o, 64);
  if ((threadIdx.x & 63) == 0) ss[threadIdx.x >> 6] = s;
  __syncthreads();
  if (threadIdx.x == 0) mproj[j] = ss[0] + ss[1] + ss[2] + ss[3];
}

// ---- build KT[j'][k] row-major gate-interleaved transpose, fp16 -------------
// j' = 4*u + g  <->  source col g*2048+u.
__global__ __launch_bounds__(256) void build_kt16(
    const float* __restrict__ src, US* __restrict__ t16)
{
  __shared__ float tile[64][65];
  const int jblk = blockIdx.x >> 5;       // 0..127
  const int kblk = blockIdx.x & 31;       // 0..31
  const int j0 = jblk * 64;
  const int u0 = j0 >> 2;
  const int k0 = kblk * 64;
  const int tid = threadIdx.x;
  const int cc = tid & 63;
  const int g = cc >> 4, uo = cc & 15;
  const int col = g * 2048 + u0 + uo;
  const int kl0 = tid >> 6;
  #pragma unroll
  for (int r = 0; r < 16; ++r) {
    int kl = r * 4 + kl0;
    tile[4 * uo + g][kl] = src[(size_t)(k0 + kl) * 8192 + col];
  }
  __syncthreads();
  const int kl = tid & 63;
  const int jl0 = tid >> 6;
  #pragma unroll
  for (int r = 0; r < 16; ++r) {
    int jl = r * 4 + jl0;
    t16[(size_t)(j0 + jl) * 2048 + (size_t)(k0 + kl)] = f2h(tile[jl][kl]);
  }
}

// ---- build BOTH fragment-linear fp16 weight sets in one pass ----------------
// tR = frag(R), tS = frag(K+R).  One read of Kmat+Rmat total.
// lin = ((jg*64+kc)*64+l)*8+e ; jg=j'>>4; kc=k>>5; l=((k>>3)&3)*16+(j'&15); e=k&7
__global__ __launch_bounds__(256) void build_wfrag16_dual(
    const float* __restrict__ Rsrc, const float* __restrict__ Ksrc,
    US* __restrict__ tR, US* __restrict__ tS)
{
  __shared__ float tileR[64][68];         // [j'local][k_local]
  __shared__ float tileS[64][68];
  const int ub = blockIdx.x >> 5;         // 0..127 (16 units each)
  const int kb = blockIdx.x & 31;         // 0..31  (64 k each)
  const int u0 = ub * 16, k0 = kb * 64;
  const int jg0 = ub * 4, kc0 = kb * 2;
  const int tid = threadIdx.x;

  const int g = tid >> 6, r2 = (tid >> 2) & 15, c4 = tid & 3;
  #pragma unroll
  for (int rr = 0; rr < 4; ++rr) {
    int row = rr * 16 + r2;
    size_t off = (size_t)(k0 + row) * 8192 + g * 2048 + u0 + c4 * 4;
    float4 v = *reinterpret_cast<const float4*>(Rsrc + off);
    float4 w = *reinterpret_cast<const float4*>(Ksrc + off);
    tileR[4 * (c4 * 4 + 0) + g][row] = v.x;
    tileR[4 * (c4 * 4 + 1) + g][row] = v.y;
    tileR[4 * (c4 * 4 + 2) + g][row] = v.z;
    tileR[4 * (c4 * 4 + 3) + g][row] = v.w;
    tileS[4 * (c4 * 4 + 0) + g][row] = v.x + w.x;
    tileS[4 * (c4 * 4 + 1) + g][row] = v.y + w.y;
    tileS[4 * (c4 * 4 + 2) + g][row] = v.z + w.z;
    tileS[4 * (c4 * 4 + 3) + g][row] = v.w + w.w;
  }
  __syncthreads();

  #pragma unroll
  for (int it = 0; it < 2; ++it) {
    int idx = it * 256 + tid;
    int l = idx & 63, kcl = (idx >> 6) & 1, jgl = idx >> 7;
    int jloc = jgl * 16 + (l & 15);
    int kl = kcl * 32 + (l >> 4) * 8;
    size_t base = (((size_t)(jg0 + jgl) * 64 + (kc0 + kcl)) * 64 + l) * 8;
    {
      float4 v0 = *reinterpret_cast<const float4*>(&tileR[jloc][kl]);
      float4 v1 = *reinterpret_cast<const float4*>(&tileR[jloc][kl + 4]);
      float f[8] = {v0.x, v0.y, v0.z, v0.w, v1.x, v1.y, v1.z, v1.w};
      unsigned int hp[4];
      #pragma unroll
      for (int q = 0; q < 4; ++q)
        hp[q] = (unsigned int)f2h(f[2 * q]) | ((unsigned int)f2h(f[2 * q + 1]) << 16);
      *reinterpret_cast<uint4*>(tR + base) = make_uint4(hp[0], hp[1], hp[2], hp[3]);
    }
    {
      float4 v0 = *reinterpret_cast<const float4*>(&tileS[jloc][kl]);
      float4 v1 = *reinterpret_cast<const float4*>(&tileS[jloc][kl + 4]);
      float f[8] = {v0.x, v0.y, v0.z, v0.w, v1.x, v1.y, v1.z, v1.w};
      unsigned int hp[4];
      #pragma unroll
      for (int q = 0; q < 4; ++q)
        hp[q] = (unsigned int)f2h(f[2 * q]) | ((unsigned int)f2h(f[2 * q + 1]) << 16);
      *reinterpret_cast<uint4*>(tS + base) = make_uint4(hp[0], hp[1], hp[2], hp[3]);
    }
  }
}

// ---- 128-row tiled GEMM, fp16 2-term: C = (Ah+Al) @ B^T ---------------------
// LDS-staged via global_load_lds + XOR swizzle + XCD block swizzle.
// EPI 0: pca (sub mproj, row remap b*64+t -> t*32+b, fp16 hi/lo split store)
// EPI 1: fp16 single store.
template<int NT, int EPI>
__global__ __launch_bounds__(256, 2) void gemm128h(
    const US* __restrict__ Ah, const US* __restrict__ Al,
    const US* __restrict__ B, const float* __restrict__ mproj,
    US* __restrict__ out0, US* __restrict__ out1,
    int MB, int ldo)
{
  constexpr int BN = NT * 32;
  __shared__ US sAh[128 * 64], sAl[128 * 64];
  __shared__ US sB[BN * 64];
  const int tid = threadIdx.x;
  const int w = tid >> 6, l = tid & 63;
  const int l16 = l & 15, lq = l >> 4;
  const int cpx = gridDim.x >> 3;
  const int swz = (blockIdx.x & 7) * cpx + (blockIdx.x >> 3);
  const int bm = swz % MB, bn = swz / MB;
  const int wm = w & 1, wn = w >> 1;
  const int AR0 = bm * 128, BR0 = bn * BN;

  f32x4 acc[4][NT];
  #pragma unroll
  for (int i = 0; i < 4; ++i)
    #pragma unroll
    for (int j = 0; j < NT; ++j) acc[i][j] = {0.f, 0.f, 0.f, 0.f};

  for (int k0 = 0; k0 < 2048; k0 += 64) {
    {
      #pragma unroll
      for (int i = 0; i < 4; ++i) {          // A tiles: 128 rows, hi+lo
        int c = (w * 4 + i) * 64 + l;
        int row = c >> 3, kc = c & 7;
        size_t go = (size_t)(AR0 + row) * 2048 + (k0 + ((kc ^ (row & 7)) << 3));
        gl_lds16(Ah + go, sAh + (w * 4 + i) * 512);
        gl_lds16(Al + go, sAl + (w * 4 + i) * 512);
      }
      constexpr int IPW = BN >> 5;           // B tiles: BN rows
      #pragma unroll
      for (int i = 0; i < IPW; ++i) {
        int c = (w * IPW + i) * 64 + l;
        int row = c >> 3, kc = c & 7;
        size_t go = (size_t)(BR0 + row) * 2048 + (k0 + ((kc ^ (row & 7)) << 3));
        gl_lds16(B + go, sB + (w * IPW + i) * 512);
      }
    }
    __syncthreads();
    #pragma unroll
    for (int ks = 0; ks < 2; ++ks) {
      const int kb = ks * 64 + lq * 16;
      f16x8 ah[4], al[4], bb[NT];
      #pragma unroll
      for (int mt = 0; mt < 4; ++mt) {
        int r = wm * 64 + mt * 16 + l16;
        int off = r * 64 + ((kb ^ ((r & 7) << 4)) >> 1);
        ah[mt] = *reinterpret_cast<const f16x8*>(sAh + off);
        al[mt] = *reinterpret_cast<const f16x8*>(sAl + off);
      }
      #pragma unroll
      for (int nt = 0; nt < NT; ++nt) {
        int r = wn * (BN / 2) + nt * 16 + l16;
        int off = r * 64 + ((kb ^ ((r & 7) << 4)) >> 1);
        bb[nt] = *reinterpret_cast<const f16x8*>(sB + off);
      }
      #pragma unroll
      for (int mt = 0; mt < 4; ++mt)
        #pragma unroll
        for (int nt = 0; nt < NT; ++nt) {
          acc[mt][nt] = MFMA16(ah[mt], bb[nt], acc[mt][nt]);
          acc[mt][nt] = MFMA16(al[mt], bb[nt], acc[mt][nt]);
        }
    }
    __syncthreads();
  }

  #pragma unroll
  for (int mt = 0; mt < 4; ++mt)
    #pragma unroll
    for (int nt = 0; nt < NT; ++nt) {
      int j = BR0 + wn * (BN / 2) + nt * 16 + l16;
      float mp = (EPI == 0) ? mproj[j] : 0.f;
      #pragma unroll
      for (int r = 0; r < 4; ++r) {
        int m = AR0 + wm * 64 + mt * 16 + lq * 4 + r;
        float v = acc[mt][nt][r] - mp;
        if constexpr (EPI == 0) {
          int t = m & 63, b = m >> 6;
          size_t o = (size_t)(t * 32 + b) * ldo + j;
          US hv = f2h(v);
          out0[o] = hv;
          out1[o] = f2h(v - h2f(hv));
        } else {
          out0[(size_t)m * ldo + j] = f2h(v);
        }
      }
    }
}

// ---- one LSTM step: z = zx + h @ W'^T + bias ; fused cell update -----------
// Single-fp16 h and W, fragment-linear: all loads coalesced 1KB wave loads.
// grid 512 blocks (jg: 16 j' = 4 units), 512 thr = 8 waves = 8-way split-K.
__global__ __launch_bounds__(512, 4) void lstm_step16(
    const US* __restrict__ hf,                                    // frag (32,2048)
    const US* __restrict__ wf,                                    // frag (8192,2048)
    const US* __restrict__ zx,                                    // fp16 (32,8192) or null
    const float* __restrict__ bias, float* __restrict__ cst,
    US* __restrict__ ho,                                          // frag (32,2048)
    float* __restrict__ pred, int p)
{
  __shared__ float red[7][64][9];
  __shared__ float zbuf[32][17];
  const int tid = threadIdx.x;
  const int kq = tid >> 6, l = tid & 63;
  const int jg = blockIdx.x;
  const int l16 = l & 15, lq = l >> 4;

  const US* wp = wf + (((size_t)jg * 64 + kq * 8) * 64 + l) * 8;
  const US* ah = hf + (((size_t)kq * 16) * 64 + l) * 8;

  f32x4 acc0 = {0.f,0.f,0.f,0.f}, acc1 = {0.f,0.f,0.f,0.f};
  #pragma unroll
  for (int c = 0; c < 8; ++c) {
    f16x8 wv = *reinterpret_cast<const f16x8*>(wp + c * 512);
    f16x8 a0 = *reinterpret_cast<const f16x8*>(ah + c * 1024);
    f16x8 a1 = *reinterpret_cast<const f16x8*>(ah + c * 1024 + 512);
    acc0 = MFMA16(a0, wv, acc0);
    acc1 = MFMA16(a1, wv, acc1);
  }

  if (kq > 0) {
    #pragma unroll
    for (int r = 0; r < 4; ++r) {
      red[kq - 1][l][r]     = acc0[r];
      red[kq - 1][l][r + 4] = acc1[r];
    }
  }
  __syncthreads();
  if (kq == 0) {
    #pragma unroll
    for (int q = 0; q < 7; ++q)
      #pragma unroll
      for (int r = 0; r < 4; ++r) {
        acc0[r] += red[q][l][r];
        acc1[r] += red[q][l][r + 4];
      }
    #pragma unroll
    for (int r = 0; r < 4; ++r) {
      zbuf[lq * 4 + r][l16]      = acc0[r];
      zbuf[lq * 4 + r + 16][l16] = acc1[r];
    }
  }
  __syncthreads();

  if (tid < 128) {
    int m = tid >> 2, ul = tid & 3;
    int u = jg * 4 + ul;
    float zi = zbuf[m][ul * 4 + 0] + bias[u];
    float zf = zbuf[m][ul * 4 + 1] + bias[u + 2048];
    float zg = zbuf[m][ul * 4 + 2] + bias[u + 4096];
    float zo = zbuf[m][ul * 4 + 3] + bias[u + 6144];
    if (zx) {
      ushort4 zr = *reinterpret_cast<const ushort4*>(
          zx + (size_t)m * 8192 + (size_t)u * 4);
      zi += h2f(zr.x); zf += h2f(zr.y); zg += h2f(zr.z); zo += h2f(zr.w);
    }
    float gi = 1.f / (1.f + expf(-zi));
    float gf = 1.f / (1.f + expf(-zf));
    float gg = tanhf(zg);
    float go = 1.f / (1.f + expf(-zo));
    float cn = gf * cst[m * 2048 + u] + gi * gg;
    float hn = go * tanhf(cn);
    cst[m * 2048 + u] = cn;
    // h write in fragment-linear layout for next step's A loads
    int kc = u >> 5, mh = m >> 4;
    int lw = ((u >> 3) & 3) * 16 + (m & 15);
    int e = u & 7;
    ho[(((size_t)kc * 2 + mh) * 64 + lw) * 8 + e] = f2h(hn);
    if (p >= 0) pred[(size_t)(m * 24 + p) * 2048 + u] = hn;
  }
}

// ============================================================================
extern "C" void kernel_launch(void* const* d_in, const int* in_sizes, int n_in,
                              void* d_out, int out_size, void* d_ws, size_t ws_size,
                              hipStream_t stream)
{
  const float* inputs = (const float*)d_in[0];   // (32,64,2048,1)
  const float* comp   = (const float*)d_in[1];   // (2048,2048)
  const float* mean   = (const float*)d_in[2];   // (2048,)
  const float* Kmat   = (const float*)d_in[3];   // (2048,8192)
  const float* Rmat   = (const float*)d_in[4];   // (2048,8192)
  const float* bias   = (const float*)d_in[5];   // (8192,)
  float* out = (float*)d_out;                    // (32,24,2048)

  // ---- workspace layout (~137 MiB, within the proven envelope) ----
  const size_t MiB = 1024 * 1024;
  char* base = (char*)d_ws;
  US* zx16     = (US*)(base);                    // [0,32)   fp16 2048x8192
  US* KT       = (US*)(base + 32 * MiB);         // [32,64)  row-major K^T fp16
  US* WSTf     = KT;                             // frag (K+R), over dead KT
  US* RTf      = (US*)(base + 64 * MiB);         // [64,96)  frag R fp16
  US* flat_hi  = (US*)(base + 96 * MiB);         // [96,104)
  US* flat_lo  = (US*)(base + 104 * MiB);        // [104,112)
  US* comp16   = (US*)(base + 112 * MiB);        // [112,120)
  US* xs_hi    = (US*)(base + 120 * MiB);        // [120,128)
  US* xs_lo    = (US*)(base + 128 * MiB);        // [128,136)
  char* Mz = base + 136 * MiB;
  float* mproj = (float*)(Mz);                   // 8 KB
  float* cbuf  = (float*)(Mz + 64 * 1024);       // 256 KB fp32 c-state
  US* hh[2];
  hh[0] = (US*)(Mz + 320 * 1024);                // 128 KB each
  hh[1] = (US*)(Mz + 448 * 1024);

  // ---- prep ----
  split16_kernel<<<4096, 256, 0, stream>>>(inputs, flat_hi, flat_lo, 1048576);
  cvt16_kernel<<<4096, 256, 0, stream>>>(comp, comp16, 1048576);
  mproj_kernel<<<2048, 256, 0, stream>>>(mean, comp, mproj);
  build_kt16<<<4096, 256, 0, stream>>>(Kmat, KT);
  zero_kernel<<<256, 256, 0, stream>>>(cbuf, hh[0]);

  // xs = (flat - mean) @ comp^T  (2048 x 2048), rows remapped to t*32+b
  gemm128h<2, 0><<<512, 256, 0, stream>>>(flat_hi, flat_lo, comp16,
                                          mproj, xs_hi, xs_lo, 16, 2048);
  // zx = xs @ K^T  (2048 x 8192, gate-interleaved cols), fp16 store
  gemm128h<4, 1><<<1024, 256, 0, stream>>>(xs_hi, xs_lo, KT,
                                           nullptr, zx16, nullptr, 16, 8192);
  // RTf (encoder) + WSTf (decoder, over dead KT) in ONE pass over K+R
  build_wfrag16_dual<<<4096, 256, 0, stream>>>(Rmat, Kmat, RTf, WSTf);

  // ---- 64 encoder steps: z = zx[s] + h @ R^T ----
  for (int s = 0; s < 64; ++s) {
    int par = s & 1;
    lstm_step16<<<512, 512, 0, stream>>>(hh[par], RTf,
                                         zx16 + (size_t)s * 32 * 8192,
                                         bias, cbuf, hh[1 - par],
                                         out, -1);
  }
  // ---- 24 decoder steps: z = h @ (K+R)^T ----
  for (int s = 64; s < 88; ++s) {
    int par = s & 1;
    lstm_step16<<<512, 512, 0, stream>>>(hh[par], WSTf,
                                         nullptr,
                                         bias, cbuf, hh[1 - par],
                                         out, s - 64);
  }
}

// Round 12
// 955.300 us; speedup vs baseline: 2.3019x; 1.1026x over previous
//
#include <hip/hip_runtime.h>
#include <math.h>

// ============================================================================
// PCA + LSTM encoder/decoder on MI355X.  (R12 = R11 + h-broadcast halving
// [256-block step kernel] + single-pass weight transposes.)
//  - Weights: single fp16, fragment-linear (32 MiB/step stream @ ~HBM BW).
//  - h: single fp16; 256 blocks x 32 j' => h L2 traffic 64->32 MB/step.
//  - zx: fp16. Encoder x@K precomputed in ONE GEMM; decoder uses K+R summed.
//  - KT + RTf + WSTf all built in ONE pass over Kmat+Rmat.
// ============================================================================

typedef unsigned short US;
typedef __attribute__((ext_vector_type(8))) _Float16 f16x8;
typedef __attribute__((ext_vector_type(4))) float f32x4;

typedef __attribute__((address_space(3))) unsigned int as3_uint;
typedef __attribute__((address_space(1))) unsigned int as1_uint;

#define MFMA16(a, b, c) __builtin_amdgcn_mfma_f32_16x16x32_f16(a, b, c, 0, 0, 0)

__device__ __forceinline__ US f2h(float x) {      // RNE fp32 -> fp16 bits
  _Float16 h = (_Float16)x;
  return __builtin_bit_cast(US, h);
}
__device__ __forceinline__ float h2f(US u) {
  return (float)__builtin_bit_cast(_Float16, u);
}

__device__ __forceinline__ void gl_lds16(const US* g, US* l) {
  __builtin_amdgcn_global_load_lds((const as1_uint*)g, (as3_uint*)l, 16, 0, 0);
}

// ---- fp32 -> fp16 hi/lo split (PCA A operand keeps 2-term accuracy) ---------
__global__ __launch_bounds__(256) void split16_kernel(
    const float* __restrict__ in, US* __restrict__ hi, US* __restrict__ lo, int n4)
{
  int i = blockIdx.x * 256 + threadIdx.x;
  if (i >= n4) return;
  float4 v = reinterpret_cast<const float4*>(in)[i];
  US h0 = f2h(v.x), h1 = f2h(v.y), h2 = f2h(v.z), h3 = f2h(v.w);
  reinterpret_cast<ushort4*>(hi)[i] = make_ushort4(h0, h1, h2, h3);
  reinterpret_cast<ushort4*>(lo)[i] =
      make_ushort4(f2h(v.x - h2f(h0)), f2h(v.y - h2f(h1)),
                   f2h(v.z - h2f(h2)), f2h(v.w - h2f(h3)));
}

// ---- fp32 -> fp16 (single) --------------------------------------------------
__global__ __launch_bounds__(256) void cvt16_kernel(
    const float* __restrict__ in, US* __restrict__ o16, int n4)
{
  int i = blockIdx.x * 256 + threadIdx.x;
  if (i >= n4) return;
  float4 v = reinterpret_cast<const float4*>(in)[i];
  reinterpret_cast<ushort4*>(o16)[i] =
      make_ushort4(f2h(v.x), f2h(v.y), f2h(v.z), f2h(v.w));
}

// ---- zero c (fp32) and initial h (fp16) -------------------------------------
__global__ void zero_kernel(float* __restrict__ c, US* __restrict__ h0)
{
  int i = blockIdx.x * 256 + threadIdx.x;   // grid covers 65536 exactly
  c[i] = 0.f; h0[i] = 0;
}

// ---- mproj[j] = sum_k mean[k] * comp[j][k]  (fp32) --------------------------
__global__ __launch_bounds__(256) void mproj_kernel(
    const float* __restrict__ mean, const float* __restrict__ comp,
    float* __restrict__ mproj)
{
  int j = blockIdx.x;
  const float* row = comp + (size_t)j * 2048;
  float s = 0.f;
  for (int k = threadIdx.x; k < 2048; k += 256) s += mean[k] * row[k];
  __shared__ float ss[4];
  #pragma unroll
  for (int o = 32; o > 0; o >>= 1) s += __shfl_down(s, o, 64);
  if ((threadIdx.x & 63) == 0) ss[threadIdx.x >> 6] = s;
  __syncthreads();
  if (threadIdx.x == 0) mproj[j] = ss[0] + ss[1] + ss[2] + ss[3];
}

// ---- single pass over Kmat+Rmat: emit KT (row-major fp16), RTf, WSTf -------
// j' = 4*u + g <-> source col g*2048+u. frag lin = ((jg*64+kc)*64+l)*8+e.
__global__ __launch_bounds__(256) void build_weights(
    const float* __restrict__ Rsrc, const float* __restrict__ Ksrc,
    US* __restrict__ KT, US* __restrict__ tR, US* __restrict__ tS)
{
  __shared__ float tileR[64][68];         // [j'local][k_local]
  __shared__ float tileK[64][68];
  const int ub = blockIdx.x >> 5;         // 0..127 (16 units = 64 j' each)
  const int kb = blockIdx.x & 31;         // 0..31  (64 k each)
  const int u0 = ub * 16, k0 = kb * 64;
  const int j0 = ub * 64;
  const int jg0 = ub * 4, kc0 = kb * 2;
  const int tid = threadIdx.x;

  const int g = tid >> 6, r2 = (tid >> 2) & 15, c4 = tid & 3;
  #pragma unroll
  for (int rr = 0; rr < 4; ++rr) {
    int row = rr * 16 + r2;
    size_t off = (size_t)(k0 + row) * 8192 + g * 2048 + u0 + c4 * 4;
    float4 v = *reinterpret_cast<const float4*>(Rsrc + off);
    float4 w = *reinterpret_cast<const float4*>(Ksrc + off);
    tileR[4 * (c4 * 4 + 0) + g][row] = v.x;
    tileR[4 * (c4 * 4 + 1) + g][row] = v.y;
    tileR[4 * (c4 * 4 + 2) + g][row] = v.z;
    tileR[4 * (c4 * 4 + 3) + g][row] = v.w;
    tileK[4 * (c4 * 4 + 0) + g][row] = w.x;
    tileK[4 * (c4 * 4 + 1) + g][row] = w.y;
    tileK[4 * (c4 * 4 + 2) + g][row] = w.z;
    tileK[4 * (c4 * 4 + 3) + g][row] = w.w;
  }
  __syncthreads();

  // KT row-major (for the zx GEMM B operand)
  {
    const int klw = tid & 63, jl0 = tid >> 6;
    #pragma unroll
    for (int r = 0; r < 16; ++r) {
      int jl = r * 4 + jl0;
      KT[(size_t)(j0 + jl) * 2048 + (size_t)(k0 + klw)] = f2h(tileK[jl][klw]);
    }
  }
  // RTf and WSTf fragment-linear
  #pragma unroll
  for (int it = 0; it < 2; ++it) {
    int idx = it * 256 + tid;
    int l = idx & 63, kcl = (idx >> 6) & 1, jgl = idx >> 7;
    int jloc = jgl * 16 + (l & 15);
    int kl = kcl * 32 + (l >> 4) * 8;
    size_t base = (((size_t)(jg0 + jgl) * 64 + (kc0 + kcl)) * 64 + l) * 8;
    unsigned int hr[4], hs[4];
    #pragma unroll
    for (int q = 0; q < 4; ++q) {
      float r0 = tileR[jloc][kl + 2 * q],     r1 = tileR[jloc][kl + 2 * q + 1];
      float k0v = tileK[jloc][kl + 2 * q],    k1v = tileK[jloc][kl + 2 * q + 1];
      hr[q] = (unsigned int)f2h(r0) | ((unsigned int)f2h(r1) << 16);
      hs[q] = (unsigned int)f2h(r0 + k0v) | ((unsigned int)f2h(r1 + k1v) << 16);
    }
    *reinterpret_cast<uint4*>(tR + base) = make_uint4(hr[0], hr[1], hr[2], hr[3]);
    *reinterpret_cast<uint4*>(tS + base) = make_uint4(hs[0], hs[1], hs[2], hs[3]);
  }
}

// ---- 128-row tiled GEMM, fp16 2-term: C = (Ah+Al) @ B^T ---------------------
// LDS-staged via global_load_lds + XOR swizzle + XCD block swizzle.
// EPI 0: pca (sub mproj, row remap b*64+t -> t*32+b, fp16 hi/lo split store)
// EPI 1: fp16 single store.
template<int NT, int EPI>
__global__ __launch_bounds__(256, 2) void gemm128h(
    const US* __restrict__ Ah, const US* __restrict__ Al,
    const US* __restrict__ B, const float* __restrict__ mproj,
    US* __restrict__ out0, US* __restrict__ out1,
    int MB, int ldo)
{
  constexpr int BN = NT * 32;
  __shared__ US sAh[128 * 64], sAl[128 * 64];
  __shared__ US sB[BN * 64];
  const int tid = threadIdx.x;
  const int w = tid >> 6, l = tid & 63;
  const int l16 = l & 15, lq = l >> 4;
  const int cpx = gridDim.x >> 3;
  const int swz = (blockIdx.x & 7) * cpx + (blockIdx.x >> 3);
  const int bm = swz % MB, bn = swz / MB;
  const int wm = w & 1, wn = w >> 1;
  const int AR0 = bm * 128, BR0 = bn * BN;

  f32x4 acc[4][NT];
  #pragma unroll
  for (int i = 0; i < 4; ++i)
    #pragma unroll
    for (int j = 0; j < NT; ++j) acc[i][j] = {0.f, 0.f, 0.f, 0.f};

  for (int k0 = 0; k0 < 2048; k0 += 64) {
    {
      #pragma unroll
      for (int i = 0; i < 4; ++i) {          // A tiles: 128 rows, hi+lo
        int c = (w * 4 + i) * 64 + l;
        int row = c >> 3, kc = c & 7;
        size_t go = (size_t)(AR0 + row) * 2048 + (k0 + ((kc ^ (row & 7)) << 3));
        gl_lds16(Ah + go, sAh + (w * 4 + i) * 512);
        gl_lds16(Al + go, sAl + (w * 4 + i) * 512);
      }
      constexpr int IPW = BN >> 5;           // B tiles: BN rows
      #pragma unroll
      for (int i = 0; i < IPW; ++i) {
        int c = (w * IPW + i) * 64 + l;
        int row = c >> 3, kc = c & 7;
        size_t go = (size_t)(BR0 + row) * 2048 + (k0 + ((kc ^ (row & 7)) << 3));
        gl_lds16(B + go, sB + (w * IPW + i) * 512);
      }
    }
    __syncthreads();
    #pragma unroll
    for (int ks = 0; ks < 2; ++ks) {
      const int kb = ks * 64 + lq * 16;
      f16x8 ah[4], al[4], bb[NT];
      #pragma unroll
      for (int mt = 0; mt < 4; ++mt) {
        int r = wm * 64 + mt * 16 + l16;
        int off = r * 64 + ((kb ^ ((r & 7) << 4)) >> 1);
        ah[mt] = *reinterpret_cast<const f16x8*>(sAh + off);
        al[mt] = *reinterpret_cast<const f16x8*>(sAl + off);
      }
      #pragma unroll
      for (int nt = 0; nt < NT; ++nt) {
        int r = wn * (BN / 2) + nt * 16 + l16;
        int off = r * 64 + ((kb ^ ((r & 7) << 4)) >> 1);
        bb[nt] = *reinterpret_cast<const f16x8*>(sB + off);
      }
      #pragma unroll
      for (int mt = 0; mt < 4; ++mt)
        #pragma unroll
        for (int nt = 0; nt < NT; ++nt) {
          acc[mt][nt] = MFMA16(ah[mt], bb[nt], acc[mt][nt]);
          acc[mt][nt] = MFMA16(al[mt], bb[nt], acc[mt][nt]);
        }
    }
    __syncthreads();
  }

  #pragma unroll
  for (int mt = 0; mt < 4; ++mt)
    #pragma unroll
    for (int nt = 0; nt < NT; ++nt) {
      int j = BR0 + wn * (BN / 2) + nt * 16 + l16;
      float mp = (EPI == 0) ? mproj[j] : 0.f;
      #pragma unroll
      for (int r = 0; r < 4; ++r) {
        int m = AR0 + wm * 64 + mt * 16 + lq * 4 + r;
        float v = acc[mt][nt][r] - mp;
        if constexpr (EPI == 0) {
          int t = m & 63, b = m >> 6;
          size_t o = (size_t)(t * 32 + b) * ldo + j;
          US hv = f2h(v);
          out0[o] = hv;
          out1[o] = f2h(v - h2f(hv));
        } else {
          out0[(size_t)m * ldo + j] = f2h(v);
        }
      }
    }
}

// ---- one LSTM step: z = zx + h @ W'^T + bias ; fused cell update -----------
// 256 blocks (block b: 32 j' = 8 units, jg {2b,2b+1}), 512 thr = 8 waves,
// 8-way split-K; each wave handles BOTH jg -> h read once per block.
__global__ __launch_bounds__(512, 4) void lstm_step16(
    const US* __restrict__ hf,                                    // frag (32,2048)
    const US* __restrict__ wf,                                    // frag (8192,2048)
    const US* __restrict__ zx,                                    // fp16 (32,8192) or null
    const float* __restrict__ bias, float* __restrict__ cst,
    US* __restrict__ ho,                                          // frag (32,2048)
    float* __restrict__ pred, int p)
{
  __shared__ float red[7][64][17];
  __shared__ float zbuf[32][33];
  const int tid = threadIdx.x;
  const int kq = tid >> 6, l = tid & 63;
  const int b = blockIdx.x;
  const int l16 = l & 15, lq = l >> 4;

  const US* wp0 = wf + (((size_t)(2 * b) * 64 + kq * 8) * 64 + l) * 8;
  const US* wp1 = wp0 + (size_t)64 * 64 * 8;     // jg+1
  const US* ah  = hf + (((size_t)kq * 16) * 64 + l) * 8;

  f32x4 acc00 = {0.f,0.f,0.f,0.f}, acc01 = {0.f,0.f,0.f,0.f};
  f32x4 acc10 = {0.f,0.f,0.f,0.f}, acc11 = {0.f,0.f,0.f,0.f};
  #pragma unroll
  for (int c = 0; c < 8; ++c) {
    f16x8 w0 = *reinterpret_cast<const f16x8*>(wp0 + c * 512);
    f16x8 w1 = *reinterpret_cast<const f16x8*>(wp1 + c * 512);
    f16x8 a0 = *reinterpret_cast<const f16x8*>(ah + c * 1024);
    f16x8 a1 = *reinterpret_cast<const f16x8*>(ah + c * 1024 + 512);
    acc00 = MFMA16(a0, w0, acc00);
    acc10 = MFMA16(a1, w0, acc10);
    acc01 = MFMA16(a0, w1, acc01);
    acc11 = MFMA16(a1, w1, acc11);
  }

  if (kq > 0) {
    #pragma unroll
    for (int r = 0; r < 4; ++r) {
      red[kq - 1][l][r]      = acc00[r];
      red[kq - 1][l][r + 4]  = acc01[r];
      red[kq - 1][l][r + 8]  = acc10[r];
      red[kq - 1][l][r + 12] = acc11[r];
    }
  }
  __syncthreads();
  if (kq == 0) {
    #pragma unroll
    for (int q = 0; q < 7; ++q)
      #pragma unroll
      for (int r = 0; r < 4; ++r) {
        acc00[r] += red[q][l][r];
        acc01[r] += red[q][l][r + 4];
        acc10[r] += red[q][l][r + 8];
        acc11[r] += red[q][l][r + 12];
      }
    #pragma unroll
    for (int r = 0; r < 4; ++r) {
      zbuf[lq * 4 + r][l16]           = acc00[r];
      zbuf[lq * 4 + r][16 + l16]      = acc01[r];
      zbuf[16 + lq * 4 + r][l16]      = acc10[r];
      zbuf[16 + lq * 4 + r][16 + l16] = acc11[r];
    }
  }
  __syncthreads();

  if (tid < 256) {
    int m = tid >> 3, ul = tid & 7;            // 8 units per block
    int u = b * 8 + ul;
    float zi = zbuf[m][ul * 4 + 0] + bias[u];
    float zf = zbuf[m][ul * 4 + 1] + bias[u + 2048];
    float zg = zbuf[m][ul * 4 + 2] + bias[u + 4096];
    float zo = zbuf[m][ul * 4 + 3] + bias[u + 6144];
    if (zx) {
      ushort4 zr = *reinterpret_cast<const ushort4*>(
          zx + (size_t)m * 8192 + (size_t)u * 4);
      zi += h2f(zr.x); zf += h2f(zr.y); zg += h2f(zr.z); zo += h2f(zr.w);
    }
    float gi = 1.f / (1.f + expf(-zi));
    float gf = 1.f / (1.f + expf(-zf));
    float gg = tanhf(zg);
    float go = 1.f / (1.f + expf(-zo));
    float cn = gf * cst[m * 2048 + u] + gi * gg;
    float hn = go * tanhf(cn);
    cst[m * 2048 + u] = cn;
    // h write in fragment-linear layout for next step's A loads
    int kc = u >> 5, mh = m >> 4;
    int lw = ((u >> 3) & 3) * 16 + (m & 15);
    int e = u & 7;
    ho[(((size_t)kc * 2 + mh) * 64 + lw) * 8 + e] = f2h(hn);
    if (p >= 0) pred[(size_t)(m * 24 + p) * 2048 + u] = hn;
  }
}

// ============================================================================
extern "C" void kernel_launch(void* const* d_in, const int* in_sizes, int n_in,
                              void* d_out, int out_size, void* d_ws, size_t ws_size,
                              hipStream_t stream)
{
  const float* inputs = (const float*)d_in[0];   // (32,64,2048,1)
  const float* comp   = (const float*)d_in[1];   // (2048,2048)
  const float* mean   = (const float*)d_in[2];   // (2048,)
  const float* Kmat   = (const float*)d_in[3];   // (2048,8192)
  const float* Rmat   = (const float*)d_in[4];   // (2048,8192)
  const float* bias   = (const float*)d_in[5];   // (8192,)
  float* out = (float*)d_out;                    // (32,24,2048)

  // ---- workspace layout (~169 MiB, within the proven envelope) ----
  const size_t MiB = 1024 * 1024;
  char* base = (char*)d_ws;
  US* zx16     = (US*)(base);                    // [0,32)   fp16 2048x8192
  US* KT       = (US*)(base + 32 * MiB);         // [32,64)  row-major K^T fp16
  US* RTf      = (US*)(base + 64 * MiB);         // [64,96)  frag R fp16
  US* WSTf     = (US*)(base + 96 * MiB);         // [96,128) frag K+R fp16
  US* flat_hi  = (US*)(base + 128 * MiB);        // [128,136)
  US* flat_lo  = (US*)(base + 136 * MiB);        // [136,144)
  US* comp16   = (US*)(base + 144 * MiB);        // [144,152)
  US* xs_hi    = (US*)(base + 152 * MiB);        // [152,160)
  US* xs_lo    = (US*)(base + 160 * MiB);        // [160,168)
  char* Mz = base + 168 * MiB;
  float* mproj = (float*)(Mz);                   // 8 KB
  float* cbuf  = (float*)(Mz + 64 * 1024);       // 256 KB fp32 c-state
  US* hh[2];
  hh[0] = (US*)(Mz + 320 * 1024);                // 128 KB each
  hh[1] = (US*)(Mz + 448 * 1024);

  // ---- prep ----
  split16_kernel<<<4096, 256, 0, stream>>>(inputs, flat_hi, flat_lo, 1048576);
  cvt16_kernel<<<4096, 256, 0, stream>>>(comp, comp16, 1048576);
  mproj_kernel<<<2048, 256, 0, stream>>>(mean, comp, mproj);
  zero_kernel<<<256, 256, 0, stream>>>(cbuf, hh[0]);
  // KT + RTf + WSTf in ONE pass over Kmat+Rmat
  build_weights<<<4096, 256, 0, stream>>>(Rmat, Kmat, KT, RTf, WSTf);

  // xs = (flat - mean) @ comp^T  (2048 x 2048), rows remapped to t*32+b
  gemm128h<2, 0><<<512, 256, 0, stream>>>(flat_hi, flat_lo, comp16,
                                          mproj, xs_hi, xs_lo, 16, 2048);
  // zx = xs @ K^T  (2048 x 8192, gate-interleaved cols), fp16 store
  gemm128h<4, 1><<<1024, 256, 0, stream>>>(xs_hi, xs_lo, KT,
                                           nullptr, zx16, nullptr, 16, 8192);

  // ---- 64 encoder steps: z = zx[s] + h @ R^T ----
  for (int s = 0; s < 64; ++s) {
    int par = s & 1;
    lstm_step16<<<256, 512, 0, stream>>>(hh[par], RTf,
                                         zx16 + (size_t)s * 32 * 8192,
                                         bias, cbuf, hh[1 - par],
                                         out, -1);
  }
  // ---- 24 decoder steps: z = h @ (K+R)^T ----
  for (int s = 64; s < 88; ++s) {
    int par = s & 1;
    lstm_step16<<<256, 512, 0, stream>>>(hh[par], WSTf,
                                         nullptr,
                                         bias, cbuf, hh[1 - par],
                                         out, s - 64);
  }
}

// Round 13
// 806.901 us; speedup vs baseline: 2.7253x; 1.1839x over previous
//
#include <hip/hip_runtime.h>
#include <math.h>

// ============================================================================
// PCA + LSTM encoder/decoder on MI355X.  (R13 = R12 + single-fp16 GEMM A
// operands + single-barrier step reduce.)
//  - Weights: single fp16, fragment-linear (32 MiB/step @ fabric ceiling).
//  - h, xs, zx: single fp16 (one-time 2^-11 injections, damped by recurrence).
//  - 256-block step kernel, 8-way split-K, ONE barrier (direct 8-partial sum).
//  - KT + RTf + WSTf built in ONE pass over Kmat+Rmat.
// ============================================================================

typedef unsigned short US;
typedef __attribute__((ext_vector_type(8))) _Float16 f16x8;
typedef __attribute__((ext_vector_type(4))) float f32x4;

typedef __attribute__((address_space(3))) unsigned int as3_uint;
typedef __attribute__((address_space(1))) unsigned int as1_uint;

#define MFMA16(a, b, c) __builtin_amdgcn_mfma_f32_16x16x32_f16(a, b, c, 0, 0, 0)

__device__ __forceinline__ US f2h(float x) {      // RNE fp32 -> fp16 bits
  _Float16 h = (_Float16)x;
  return __builtin_bit_cast(US, h);
}
__device__ __forceinline__ float h2f(US u) {
  return (float)__builtin_bit_cast(_Float16, u);
}

__device__ __forceinline__ void gl_lds16(const US* g, US* l) {
  __builtin_amdgcn_global_load_lds((const as1_uint*)g, (as3_uint*)l, 16, 0, 0);
}

// ---- fp32 -> fp16 (single) --------------------------------------------------
__global__ __launch_bounds__(256) void cvt16_kernel(
    const float* __restrict__ in, US* __restrict__ o16, int n4)
{
  int i = blockIdx.x * 256 + threadIdx.x;
  if (i >= n4) return;
  float4 v = reinterpret_cast<const float4*>(in)[i];
  reinterpret_cast<ushort4*>(o16)[i] =
      make_ushort4(f2h(v.x), f2h(v.y), f2h(v.z), f2h(v.w));
}

// ---- zero c (fp32) and initial h (fp16) -------------------------------------
__global__ void zero_kernel(float* __restrict__ c, US* __restrict__ h0)
{
  int i = blockIdx.x * 256 + threadIdx.x;   // grid covers 65536 exactly
  c[i] = 0.f; h0[i] = 0;
}

// ---- mproj[j] = sum_k mean[k] * comp[j][k]  (fp32) --------------------------
__global__ __launch_bounds__(256) void mproj_kernel(
    const float* __restrict__ mean, const float* __restrict__ comp,
    float* __restrict__ mproj)
{
  int j = blockIdx.x;
  const float* row = comp + (size_t)j * 2048;
  float s = 0.f;
  for (int k = threadIdx.x; k < 2048; k += 256) s += mean[k] * row[k];
  __shared__ float ss[4];
  #pragma unroll
  for (int o = 32; o > 0; o >>= 1) s += __shfl_down(s, o, 64);
  if ((threadIdx.x & 63) == 0) ss[threadIdx.x >> 6] = s;
  __syncthreads();
  if (threadIdx.x == 0) mproj[j] = ss[0] + ss[1] + ss[2] + ss[3];
}

// ---- single pass over Kmat+Rmat: emit KT (row-major fp16), RTf, WSTf -------
// j' = 4*u + g <-> source col g*2048+u. frag lin = ((jg*64+kc)*64+l)*8+e.
__global__ __launch_bounds__(256) void build_weights(
    const float* __restrict__ Rsrc, const float* __restrict__ Ksrc,
    US* __restrict__ KT, US* __restrict__ tR, US* __restrict__ tS)
{
  __shared__ float tileR[64][68];         // [j'local][k_local]
  __shared__ float tileK[64][68];
  const int ub = blockIdx.x >> 5;         // 0..127 (16 units = 64 j' each)
  const int kb = blockIdx.x & 31;         // 0..31  (64 k each)
  const int u0 = ub * 16, k0 = kb * 64;
  const int j0 = ub * 64;
  const int jg0 = ub * 4, kc0 = kb * 2;
  const int tid = threadIdx.x;

  const int g = tid >> 6, r2 = (tid >> 2) & 15, c4 = tid & 3;
  #pragma unroll
  for (int rr = 0; rr < 4; ++rr) {
    int row = rr * 16 + r2;
    size_t off = (size_t)(k0 + row) * 8192 + g * 2048 + u0 + c4 * 4;
    float4 v = *reinterpret_cast<const float4*>(Rsrc + off);
    float4 w = *reinterpret_cast<const float4*>(Ksrc + off);
    tileR[4 * (c4 * 4 + 0) + g][row] = v.x;
    tileR[4 * (c4 * 4 + 1) + g][row] = v.y;
    tileR[4 * (c4 * 4 + 2) + g][row] = v.z;
    tileR[4 * (c4 * 4 + 3) + g][row] = v.w;
    tileK[4 * (c4 * 4 + 0) + g][row] = w.x;
    tileK[4 * (c4 * 4 + 1) + g][row] = w.y;
    tileK[4 * (c4 * 4 + 2) + g][row] = w.z;
    tileK[4 * (c4 * 4 + 3) + g][row] = w.w;
  }
  __syncthreads();

  // KT row-major (for the zx GEMM B operand)
  {
    const int klw = tid & 63, jl0 = tid >> 6;
    #pragma unroll
    for (int r = 0; r < 16; ++r) {
      int jl = r * 4 + jl0;
      KT[(size_t)(j0 + jl) * 2048 + (size_t)(k0 + klw)] = f2h(tileK[jl][klw]);
    }
  }
  // RTf and WSTf fragment-linear
  #pragma unroll
  for (int it = 0; it < 2; ++it) {
    int idx = it * 256 + tid;
    int l = idx & 63, kcl = (idx >> 6) & 1, jgl = idx >> 7;
    int jloc = jgl * 16 + (l & 15);
    int kl = kcl * 32 + (l >> 4) * 8;
    size_t base = (((size_t)(jg0 + jgl) * 64 + (kc0 + kcl)) * 64 + l) * 8;
    unsigned int hr[4], hs[4];
    #pragma unroll
    for (int q = 0; q < 4; ++q) {
      float r0 = tileR[jloc][kl + 2 * q],     r1 = tileR[jloc][kl + 2 * q + 1];
      float k0v = tileK[jloc][kl + 2 * q],    k1v = tileK[jloc][kl + 2 * q + 1];
      hr[q] = (unsigned int)f2h(r0) | ((unsigned int)f2h(r1) << 16);
      hs[q] = (unsigned int)f2h(r0 + k0v) | ((unsigned int)f2h(r1 + k1v) << 16);
    }
    *reinterpret_cast<uint4*>(tR + base) = make_uint4(hr[0], hr[1], hr[2], hr[3]);
    *reinterpret_cast<uint4*>(tS + base) = make_uint4(hs[0], hs[1], hs[2], hs[3]);
  }
}

// ---- 128-row tiled GEMM, single fp16: C = A @ B^T ---------------------------
// LDS-staged via global_load_lds + XOR swizzle + XCD block swizzle.
// EPI 0: pca (sub mproj, row remap b*64+t -> t*32+b, fp16 store)
// EPI 1: fp16 store at [m][ldo].
template<int NT, int EPI>
__global__ __launch_bounds__(256, 2) void gemm128h(
    const US* __restrict__ A, const US* __restrict__ B,
    const float* __restrict__ mproj,
    US* __restrict__ out0, int MB, int ldo)
{
  constexpr int BN = NT * 32;
  __shared__ US sA[128 * 64];
  __shared__ US sB[BN * 64];
  const int tid = threadIdx.x;
  const int w = tid >> 6, l = tid & 63;
  const int l16 = l & 15, lq = l >> 4;
  const int cpx = gridDim.x >> 3;
  const int swz = (blockIdx.x & 7) * cpx + (blockIdx.x >> 3);
  const int bm = swz % MB, bn = swz / MB;
  const int wm = w & 1, wn = w >> 1;
  const int AR0 = bm * 128, BR0 = bn * BN;

  f32x4 acc[4][NT];
  #pragma unroll
  for (int i = 0; i < 4; ++i)
    #pragma unroll
    for (int j = 0; j < NT; ++j) acc[i][j] = {0.f, 0.f, 0.f, 0.f};

  for (int k0 = 0; k0 < 2048; k0 += 64) {
    {
      #pragma unroll
      for (int i = 0; i < 4; ++i) {          // A tile: 128 rows
        int c = (w * 4 + i) * 64 + l;
        int row = c >> 3, kc = c & 7;
        size_t go = (size_t)(AR0 + row) * 2048 + (k0 + ((kc ^ (row & 7)) << 3));
        gl_lds16(A + go, sA + (w * 4 + i) * 512);
      }
      constexpr int IPW = BN >> 5;           // B tile: BN rows
      #pragma unroll
      for (int i = 0; i < IPW; ++i) {
        int c = (w * IPW + i) * 64 + l;
        int row = c >> 3, kc = c & 7;
        size_t go = (size_t)(BR0 + row) * 2048 + (k0 + ((kc ^ (row & 7)) << 3));
        gl_lds16(B + go, sB + (w * IPW + i) * 512);
      }
    }
    __syncthreads();
    #pragma unroll
    for (int ks = 0; ks < 2; ++ks) {
      const int kb = ks * 64 + lq * 16;
      f16x8 ah[4], bb[NT];
      #pragma unroll
      for (int mt = 0; mt < 4; ++mt) {
        int r = wm * 64 + mt * 16 + l16;
        int off = r * 64 + ((kb ^ ((r & 7) << 4)) >> 1);
        ah[mt] = *reinterpret_cast<const f16x8*>(sA + off);
      }
      #pragma unroll
      for (int nt = 0; nt < NT; ++nt) {
        int r = wn * (BN / 2) + nt * 16 + l16;
        int off = r * 64 + ((kb ^ ((r & 7) << 4)) >> 1);
        bb[nt] = *reinterpret_cast<const f16x8*>(sB + off);
      }
      #pragma unroll
      for (int mt = 0; mt < 4; ++mt)
        #pragma unroll
        for (int nt = 0; nt < NT; ++nt)
          acc[mt][nt] = MFMA16(ah[mt], bb[nt], acc[mt][nt]);
    }
    __syncthreads();
  }

  #pragma unroll
  for (int mt = 0; mt < 4; ++mt)
    #pragma unroll
    for (int nt = 0; nt < NT; ++nt) {
      int j = BR0 + wn * (BN / 2) + nt * 16 + l16;
      float mp = (EPI == 0) ? mproj[j] : 0.f;
      #pragma unroll
      for (int r = 0; r < 4; ++r) {
        int m = AR0 + wm * 64 + mt * 16 + lq * 4 + r;
        float v = acc[mt][nt][r] - mp;
        if constexpr (EPI == 0) {
          int t = m & 63, bb_ = m >> 6;
          out0[(size_t)(t * 32 + bb_) * ldo + j] = f2h(v);
        } else {
          out0[(size_t)m * ldo + j] = f2h(v);
        }
      }
    }
}

// ---- one LSTM step: z = zx + h @ W'^T + bias ; fused cell update -----------
// 256 blocks (block b: 32 j' = 8 units, jg {2b,2b+1}), 512 thr = 8 waves,
// 8-way split-K. ONE barrier: all waves write partials, cell threads sum 8.
__global__ __launch_bounds__(512, 4) void lstm_step16(
    const US* __restrict__ hf,                                    // frag (32,2048)
    const US* __restrict__ wf,                                    // frag (8192,2048)
    const US* __restrict__ zx,                                    // fp16 (32,8192) or null
    const float* __restrict__ bias, float* __restrict__ cst,
    US* __restrict__ ho,                                          // frag (32,2048)
    float* __restrict__ pred, int p)
{
  __shared__ float red[8][32][33];        // [kq][j'loc][m]
  const int tid = threadIdx.x;
  const int kq = tid >> 6, l = tid & 63;
  const int b = blockIdx.x;
  const int l16 = l & 15, lq = l >> 4;

  const US* wp0 = wf + (((size_t)(2 * b) * 64 + kq * 8) * 64 + l) * 8;
  const US* wp1 = wp0 + (size_t)64 * 64 * 8;     // jg+1
  const US* ah  = hf + (((size_t)kq * 16) * 64 + l) * 8;

  f32x4 acc00 = {0.f,0.f,0.f,0.f}, acc01 = {0.f,0.f,0.f,0.f};
  f32x4 acc10 = {0.f,0.f,0.f,0.f}, acc11 = {0.f,0.f,0.f,0.f};
  #pragma unroll
  for (int c = 0; c < 8; ++c) {
    f16x8 w0 = *reinterpret_cast<const f16x8*>(wp0 + c * 512);
    f16x8 w1 = *reinterpret_cast<const f16x8*>(wp1 + c * 512);
    f16x8 a0 = *reinterpret_cast<const f16x8*>(ah + c * 1024);
    f16x8 a1 = *reinterpret_cast<const f16x8*>(ah + c * 1024 + 512);
    acc00 = MFMA16(a0, w0, acc00);
    acc10 = MFMA16(a1, w0, acc10);
    acc01 = MFMA16(a0, w1, acc01);
    acc11 = MFMA16(a1, w1, acc11);
  }

  #pragma unroll
  for (int r = 0; r < 4; ++r) {
    red[kq][l16][lq * 4 + r]           = acc00[r];
    red[kq][16 + l16][lq * 4 + r]      = acc01[r];
    red[kq][l16][16 + lq * 4 + r]      = acc10[r];
    red[kq][16 + l16][16 + lq * 4 + r] = acc11[r];
  }
  __syncthreads();

  if (tid < 256) {
    int m = tid >> 3, ul = tid & 7;            // 8 units per block
    int u = b * 8 + ul;
    float z[4];
    #pragma unroll
    for (int g = 0; g < 4; ++g) {
      float s = bias[u + g * 2048];
      #pragma unroll
      for (int q = 0; q < 8; ++q) s += red[q][ul * 4 + g][m];
      z[g] = s;
    }
    if (zx) {
      ushort4 zr = *reinterpret_cast<const ushort4*>(
          zx + (size_t)m * 8192 + (size_t)u * 4);
      z[0] += h2f(zr.x); z[1] += h2f(zr.y); z[2] += h2f(zr.z); z[3] += h2f(zr.w);
    }
    float gi = 1.f / (1.f + expf(-z[0]));
    float gf = 1.f / (1.f + expf(-z[1]));
    float gg = tanhf(z[2]);
    float go = 1.f / (1.f + expf(-z[3]));
    float cn = gf * cst[m * 2048 + u] + gi * gg;
    float hn = go * tanhf(cn);
    cst[m * 2048 + u] = cn;
    // h write in fragment-linear layout for next step's A loads
    int kc = u >> 5, mh = m >> 4;
    int lw = ((u >> 3) & 3) * 16 + (m & 15);
    int e = u & 7;
    ho[(((size_t)kc * 2 + mh) * 64 + lw) * 8 + e] = f2h(hn);
    if (p >= 0) pred[(size_t)(m * 24 + p) * 2048 + u] = hn;
  }
}

// ============================================================================
extern "C" void kernel_launch(void* const* d_in, const int* in_sizes, int n_in,
                              void* d_out, int out_size, void* d_ws, size_t ws_size,
                              hipStream_t stream)
{
  const float* inputs = (const float*)d_in[0];   // (32,64,2048,1)
  const float* comp   = (const float*)d_in[1];   // (2048,2048)
  const float* mean   = (const float*)d_in[2];   // (2048,)
  const float* Kmat   = (const float*)d_in[3];   // (2048,8192)
  const float* Rmat   = (const float*)d_in[4];   // (2048,8192)
  const float* bias   = (const float*)d_in[5];   // (8192,)
  float* out = (float*)d_out;                    // (32,24,2048)

  // ---- workspace layout (~153 MiB, within the proven envelope) ----
  const size_t MiB = 1024 * 1024;
  char* base = (char*)d_ws;
  US* zx16     = (US*)(base);                    // [0,32)   fp16 2048x8192
  US* KT       = (US*)(base + 32 * MiB);         // [32,64)  row-major K^T fp16
  US* RTf      = (US*)(base + 64 * MiB);         // [64,96)  frag R fp16
  US* WSTf     = (US*)(base + 96 * MiB);         // [96,128) frag K+R fp16
  US* flat16   = (US*)(base + 128 * MiB);        // [128,136)
  US* comp16   = (US*)(base + 136 * MiB);        // [136,144)
  US* xs16     = (US*)(base + 144 * MiB);        // [144,152)
  char* Mz = base + 152 * MiB;
  float* mproj = (float*)(Mz);                   // 8 KB
  float* cbuf  = (float*)(Mz + 64 * 1024);       // 256 KB fp32 c-state
  US* hh[2];
  hh[0] = (US*)(Mz + 320 * 1024);                // 128 KB each
  hh[1] = (US*)(Mz + 448 * 1024);

  // ---- prep ----
  cvt16_kernel<<<4096, 256, 0, stream>>>(inputs, flat16, 1048576);
  cvt16_kernel<<<4096, 256, 0, stream>>>(comp, comp16, 1048576);
  mproj_kernel<<<2048, 256, 0, stream>>>(mean, comp, mproj);
  zero_kernel<<<256, 256, 0, stream>>>(cbuf, hh[0]);
  // KT + RTf + WSTf in ONE pass over Kmat+Rmat
  build_weights<<<4096, 256, 0, stream>>>(Rmat, Kmat, KT, RTf, WSTf);

  // xs = (flat - mean) @ comp^T  (2048 x 2048), rows remapped to t*32+b
  gemm128h<2, 0><<<512, 256, 0, stream>>>(flat16, comp16, mproj,
                                          xs16, 16, 2048);
  // zx = xs @ K^T  (2048 x 8192, gate-interleaved cols), fp16 store
  gemm128h<4, 1><<<1024, 256, 0, stream>>>(xs16, KT, nullptr,
                                           zx16, 16, 8192);

  // ---- 64 encoder steps: z = zx[s] + h @ R^T ----
  for (int s = 0; s < 64; ++s) {
    int par = s & 1;
    lstm_step16<<<256, 512, 0, stream>>>(hh[par], RTf,
                                         zx16 + (size_t)s * 32 * 8192,
                                         bias, cbuf, hh[1 - par],
                                         out, -1);
  }
  // ---- 24 decoder steps: z = h @ (K+R)^T ----
  for (int s = 64; s < 88; ++s) {
    int par = s & 1;
    lstm_step16<<<256, 512, 0, stream>>>(hh[par], WSTf,
                                         nullptr,
                                         bias, cbuf, hh[1 - par],
                                         out, s - 64);
  }
}

// Round 14
// 777.573 us; speedup vs baseline: 2.8281x; 1.0377x over previous
//
#include <hip/hip_runtime.h>
#include <math.h>

// ============================================================================
// PCA + LSTM encoder/decoder on MI355X.  (R14 = R13 + epilogue-load hoisting
// in the step kernel: bias/zx/c prefetched before the MFMA phase so their
// latency hides under the 32 MiB weight stream.)
//  - Weights: single fp16, fragment-linear (32 MiB/step @ ~BW floor).
//  - h, xs, zx: single fp16. 256-block step kernel, 8-way split-K, 1 barrier.
//  - KT + RTf + WSTf built in ONE pass over Kmat+Rmat.
// ============================================================================

typedef unsigned short US;
typedef __attribute__((ext_vector_type(8))) _Float16 f16x8;
typedef __attribute__((ext_vector_type(4))) float f32x4;

typedef __attribute__((address_space(3))) unsigned int as3_uint;
typedef __attribute__((address_space(1))) unsigned int as1_uint;

#define MFMA16(a, b, c) __builtin_amdgcn_mfma_f32_16x16x32_f16(a, b, c, 0, 0, 0)

__device__ __forceinline__ US f2h(float x) {      // RNE fp32 -> fp16 bits
  _Float16 h = (_Float16)x;
  return __builtin_bit_cast(US, h);
}
__device__ __forceinline__ float h2f(US u) {
  return (float)__builtin_bit_cast(_Float16, u);
}

__device__ __forceinline__ void gl_lds16(const US* g, US* l) {
  __builtin_amdgcn_global_load_lds((const as1_uint*)g, (as3_uint*)l, 16, 0, 0);
}

// ---- fp32 -> fp16 (single) --------------------------------------------------
__global__ __launch_bounds__(256) void cvt16_kernel(
    const float* __restrict__ in, US* __restrict__ o16, int n4)
{
  int i = blockIdx.x * 256 + threadIdx.x;
  if (i >= n4) return;
  float4 v = reinterpret_cast<const float4*>(in)[i];
  reinterpret_cast<ushort4*>(o16)[i] =
      make_ushort4(f2h(v.x), f2h(v.y), f2h(v.z), f2h(v.w));
}

// ---- zero c (fp32) and initial h (fp16) -------------------------------------
__global__ void zero_kernel(float* __restrict__ c, US* __restrict__ h0)
{
  int i = blockIdx.x * 256 + threadIdx.x;   // grid covers 65536 exactly
  c[i] = 0.f; h0[i] = 0;
}

// ---- mproj[j] = sum_k mean[k] * comp[j][k]  (fp32) --------------------------
__global__ __launch_bounds__(256) void mproj_kernel(
    const float* __restrict__ mean, const float* __restrict__ comp,
    float* __restrict__ mproj)
{
  int j = blockIdx.x;
  const float* row = comp + (size_t)j * 2048;
  float s = 0.f;
  for (int k = threadIdx.x; k < 2048; k += 256) s += mean[k] * row[k];
  __shared__ float ss[4];
  #pragma unroll
  for (int o = 32; o > 0; o >>= 1) s += __shfl_down(s, o, 64);
  if ((threadIdx.x & 63) == 0) ss[threadIdx.x >> 6] = s;
  __syncthreads();
  if (threadIdx.x == 0) mproj[j] = ss[0] + ss[1] + ss[2] + ss[3];
}

// ---- single pass over Kmat+Rmat: emit KT (row-major fp16), RTf, WSTf -------
// j' = 4*u + g <-> source col g*2048+u. frag lin = ((jg*64+kc)*64+l)*8+e.
__global__ __launch_bounds__(256) void build_weights(
    const float* __restrict__ Rsrc, const float* __restrict__ Ksrc,
    US* __restrict__ KT, US* __restrict__ tR, US* __restrict__ tS)
{
  __shared__ float tileR[64][68];         // [j'local][k_local]
  __shared__ float tileK[64][68];
  const int ub = blockIdx.x >> 5;         // 0..127 (16 units = 64 j' each)
  const int kb = blockIdx.x & 31;         // 0..31  (64 k each)
  const int u0 = ub * 16, k0 = kb * 64;
  const int j0 = ub * 64;
  const int jg0 = ub * 4, kc0 = kb * 2;
  const int tid = threadIdx.x;

  const int g = tid >> 6, r2 = (tid >> 2) & 15, c4 = tid & 3;
  #pragma unroll
  for (int rr = 0; rr < 4; ++rr) {
    int row = rr * 16 + r2;
    size_t off = (size_t)(k0 + row) * 8192 + g * 2048 + u0 + c4 * 4;
    float4 v = *reinterpret_cast<const float4*>(Rsrc + off);
    float4 w = *reinterpret_cast<const float4*>(Ksrc + off);
    tileR[4 * (c4 * 4 + 0) + g][row] = v.x;
    tileR[4 * (c4 * 4 + 1) + g][row] = v.y;
    tileR[4 * (c4 * 4 + 2) + g][row] = v.z;
    tileR[4 * (c4 * 4 + 3) + g][row] = v.w;
    tileK[4 * (c4 * 4 + 0) + g][row] = w.x;
    tileK[4 * (c4 * 4 + 1) + g][row] = w.y;
    tileK[4 * (c4 * 4 + 2) + g][row] = w.z;
    tileK[4 * (c4 * 4 + 3) + g][row] = w.w;
  }
  __syncthreads();

  // KT row-major (for the zx GEMM B operand)
  {
    const int klw = tid & 63, jl0 = tid >> 6;
    #pragma unroll
    for (int r = 0; r < 16; ++r) {
      int jl = r * 4 + jl0;
      KT[(size_t)(j0 + jl) * 2048 + (size_t)(k0 + klw)] = f2h(tileK[jl][klw]);
    }
  }
  // RTf and WSTf fragment-linear
  #pragma unroll
  for (int it = 0; it < 2; ++it) {
    int idx = it * 256 + tid;
    int l = idx & 63, kcl = (idx >> 6) & 1, jgl = idx >> 7;
    int jloc = jgl * 16 + (l & 15);
    int kl = kcl * 32 + (l >> 4) * 8;
    size_t base = (((size_t)(jg0 + jgl) * 64 + (kc0 + kcl)) * 64 + l) * 8;
    unsigned int hr[4], hs[4];
    #pragma unroll
    for (int q = 0; q < 4; ++q) {
      float r0 = tileR[jloc][kl + 2 * q],     r1 = tileR[jloc][kl + 2 * q + 1];
      float k0v = tileK[jloc][kl + 2 * q],    k1v = tileK[jloc][kl + 2 * q + 1];
      hr[q] = (unsigned int)f2h(r0) | ((unsigned int)f2h(r1) << 16);
      hs[q] = (unsigned int)f2h(r0 + k0v) | ((unsigned int)f2h(r1 + k1v) << 16);
    }
    *reinterpret_cast<uint4*>(tR + base) = make_uint4(hr[0], hr[1], hr[2], hr[3]);
    *reinterpret_cast<uint4*>(tS + base) = make_uint4(hs[0], hs[1], hs[2], hs[3]);
  }
}

// ---- 128-row tiled GEMM, single fp16: C = A @ B^T ---------------------------
// LDS-staged via global_load_lds + XOR swizzle + XCD block swizzle.
// EPI 0: pca (sub mproj, row remap b*64+t -> t*32+b, fp16 store)
// EPI 1: fp16 store at [m][ldo].
template<int NT, int EPI>
__global__ __launch_bounds__(256, 2) void gemm128h(
    const US* __restrict__ A, const US* __restrict__ B,
    const float* __restrict__ mproj,
    US* __restrict__ out0, int MB, int ldo)
{
  constexpr int BN = NT * 32;
  __shared__ US sA[128 * 64];
  __shared__ US sB[BN * 64];
  const int tid = threadIdx.x;
  const int w = tid >> 6, l = tid & 63;
  const int l16 = l & 15, lq = l >> 4;
  const int cpx = gridDim.x >> 3;
  const int swz = (blockIdx.x & 7) * cpx + (blockIdx.x >> 3);
  const int bm = swz % MB, bn = swz / MB;
  const int wm = w & 1, wn = w >> 1;
  const int AR0 = bm * 128, BR0 = bn * BN;

  f32x4 acc[4][NT];
  #pragma unroll
  for (int i = 0; i < 4; ++i)
    #pragma unroll
    for (int j = 0; j < NT; ++j) acc[i][j] = {0.f, 0.f, 0.f, 0.f};

  for (int k0 = 0; k0 < 2048; k0 += 64) {
    {
      #pragma unroll
      for (int i = 0; i < 4; ++i) {          // A tile: 128 rows
        int c = (w * 4 + i) * 64 + l;
        int row = c >> 3, kc = c & 7;
        size_t go = (size_t)(AR0 + row) * 2048 + (k0 + ((kc ^ (row & 7)) << 3));
        gl_lds16(A + go, sA + (w * 4 + i) * 512);
      }
      constexpr int IPW = BN >> 5;           // B tile: BN rows
      #pragma unroll
      for (int i = 0; i < IPW; ++i) {
        int c = (w * IPW + i) * 64 + l;
        int row = c >> 3, kc = c & 7;
        size_t go = (size_t)(BR0 + row) * 2048 + (k0 + ((kc ^ (row & 7)) << 3));
        gl_lds16(B + go, sB + (w * IPW + i) * 512);
      }
    }
    __syncthreads();
    #pragma unroll
    for (int ks = 0; ks < 2; ++ks) {
      const int kb = ks * 64 + lq * 16;
      f16x8 ah[4], bb[NT];
      #pragma unroll
      for (int mt = 0; mt < 4; ++mt) {
        int r = wm * 64 + mt * 16 + l16;
        int off = r * 64 + ((kb ^ ((r & 7) << 4)) >> 1);
        ah[mt] = *reinterpret_cast<const f16x8*>(sA + off);
      }
      #pragma unroll
      for (int nt = 0; nt < NT; ++nt) {
        int r = wn * (BN / 2) + nt * 16 + l16;
        int off = r * 64 + ((kb ^ ((r & 7) << 4)) >> 1);
        bb[nt] = *reinterpret_cast<const f16x8*>(sB + off);
      }
      #pragma unroll
      for (int mt = 0; mt < 4; ++mt)
        #pragma unroll
        for (int nt = 0; nt < NT; ++nt)
          acc[mt][nt] = MFMA16(ah[mt], bb[nt], acc[mt][nt]);
    }
    __syncthreads();
  }

  #pragma unroll
  for (int mt = 0; mt < 4; ++mt)
    #pragma unroll
    for (int nt = 0; nt < NT; ++nt) {
      int j = BR0 + wn * (BN / 2) + nt * 16 + l16;
      float mp = (EPI == 0) ? mproj[j] : 0.f;
      #pragma unroll
      for (int r = 0; r < 4; ++r) {
        int m = AR0 + wm * 64 + mt * 16 + lq * 4 + r;
        float v = acc[mt][nt][r] - mp;
        if constexpr (EPI == 0) {
          int t = m & 63, bb_ = m >> 6;
          out0[(size_t)(t * 32 + bb_) * ldo + j] = f2h(v);
        } else {
          out0[(size_t)m * ldo + j] = f2h(v);
        }
      }
    }
}

// ---- one LSTM step: z = zx + h @ W'^T + bias ; fused cell update -----------
// 256 blocks (block b: 32 j' = 8 units, jg {2b,2b+1}), 512 thr = 8 waves,
// 8-way split-K, ONE barrier. Epilogue inputs (bias/zx/c) prefetched BEFORE
// the MFMA phase so their L3 latency hides under the weight stream.
__global__ __launch_bounds__(512, 4) void lstm_step16(
    const US* __restrict__ hf,                                    // frag (32,2048)
    const US* __restrict__ wf,                                    // frag (8192,2048)
    const US* __restrict__ zx,                                    // fp16 (32,8192) or null
    const float* __restrict__ bias, float* __restrict__ cst,
    US* __restrict__ ho,                                          // frag (32,2048)
    float* __restrict__ pred, int p)
{
  __shared__ float red[8][32][33];        // [kq][j'loc][m]
  const int tid = threadIdx.x;
  const int kq = tid >> 6, l = tid & 63;
  const int b = blockIdx.x;
  const int l16 = l & 15, lq = l >> 4;
  const bool cell = (tid < 256);
  const int m = tid >> 3, ul = tid & 7;   // cell-role (valid when cell)
  const int u = b * 8 + ul;

  // ---- EARLY prefetch of epilogue inputs (latency hides under MFMA phase) --
  float pz0 = 0.f, pz1 = 0.f, pz2 = 0.f, pz3 = 0.f, cprev = 0.f;
  if (cell) {
    pz0 = bias[u];
    pz1 = bias[u + 2048];
    pz2 = bias[u + 4096];
    pz3 = bias[u + 6144];
    if (zx) {
      ushort4 zr = *reinterpret_cast<const ushort4*>(
          zx + (size_t)m * 8192 + (size_t)u * 4);
      pz0 += h2f(zr.x); pz1 += h2f(zr.y); pz2 += h2f(zr.z); pz3 += h2f(zr.w);
    }
    cprev = cst[m * 2048 + u];
  }

  const US* wp0 = wf + (((size_t)(2 * b) * 64 + kq * 8) * 64 + l) * 8;
  const US* wp1 = wp0 + (size_t)64 * 64 * 8;     // jg+1
  const US* ah  = hf + (((size_t)kq * 16) * 64 + l) * 8;

  f32x4 acc00 = {0.f,0.f,0.f,0.f}, acc01 = {0.f,0.f,0.f,0.f};
  f32x4 acc10 = {0.f,0.f,0.f,0.f}, acc11 = {0.f,0.f,0.f,0.f};
  #pragma unroll
  for (int c = 0; c < 8; ++c) {
    f16x8 w0 = *reinterpret_cast<const f16x8*>(wp0 + c * 512);
    f16x8 w1 = *reinterpret_cast<const f16x8*>(wp1 + c * 512);
    f16x8 a0 = *reinterpret_cast<const f16x8*>(ah + c * 1024);
    f16x8 a1 = *reinterpret_cast<const f16x8*>(ah + c * 1024 + 512);
    acc00 = MFMA16(a0, w0, acc00);
    acc10 = MFMA16(a1, w0, acc10);
    acc01 = MFMA16(a0, w1, acc01);
    acc11 = MFMA16(a1, w1, acc11);
  }

  #pragma unroll
  for (int r = 0; r < 4; ++r) {
    red[kq][l16][lq * 4 + r]           = acc00[r];
    red[kq][16 + l16][lq * 4 + r]      = acc01[r];
    red[kq][l16][16 + lq * 4 + r]      = acc10[r];
    red[kq][16 + l16][16 + lq * 4 + r] = acc11[r];
  }
  __syncthreads();

  if (cell) {
    float z0 = pz0, z1 = pz1, z2 = pz2, z3 = pz3;
    #pragma unroll
    for (int q = 0; q < 8; ++q) {
      z0 += red[q][ul * 4 + 0][m];
      z1 += red[q][ul * 4 + 1][m];
      z2 += red[q][ul * 4 + 2][m];
      z3 += red[q][ul * 4 + 3][m];
    }
    float gi = 1.f / (1.f + expf(-z0));
    float gf = 1.f / (1.f + expf(-z1));
    float gg = tanhf(z2);
    float go = 1.f / (1.f + expf(-z3));
    float cn = gf * cprev + gi * gg;
    float hn = go * tanhf(cn);
    cst[m * 2048 + u] = cn;
    // h write in fragment-linear layout for next step's A loads
    int kc = u >> 5, mh = m >> 4;
    int lw = ((u >> 3) & 3) * 16 + (m & 15);
    int e = u & 7;
    ho[(((size_t)kc * 2 + mh) * 64 + lw) * 8 + e] = f2h(hn);
    if (p >= 0) pred[(size_t)(m * 24 + p) * 2048 + u] = hn;
  }
}

// ============================================================================
extern "C" void kernel_launch(void* const* d_in, const int* in_sizes, int n_in,
                              void* d_out, int out_size, void* d_ws, size_t ws_size,
                              hipStream_t stream)
{
  const float* inputs = (const float*)d_in[0];   // (32,64,2048,1)
  const float* comp   = (const float*)d_in[1];   // (2048,2048)
  const float* mean   = (const float*)d_in[2];   // (2048,)
  const float* Kmat   = (const float*)d_in[3];   // (2048,8192)
  const float* Rmat   = (const float*)d_in[4];   // (2048,8192)
  const float* bias   = (const float*)d_in[5];   // (8192,)
  float* out = (float*)d_out;                    // (32,24,2048)

  // ---- workspace layout (~153 MiB, within the proven envelope) ----
  const size_t MiB = 1024 * 1024;
  char* base = (char*)d_ws;
  US* zx16     = (US*)(base);                    // [0,32)   fp16 2048x8192
  US* KT       = (US*)(base + 32 * MiB);         // [32,64)  row-major K^T fp16
  US* RTf      = (US*)(base + 64 * MiB);         // [64,96)  frag R fp16
  US* WSTf     = (US*)(base + 96 * MiB);         // [96,128) frag K+R fp16
  US* flat16   = (US*)(base + 128 * MiB);        // [128,136)
  US* comp16   = (US*)(base + 136 * MiB);        // [136,144)
  US* xs16     = (US*)(base + 144 * MiB);        // [144,152)
  char* Mz = base + 152 * MiB;
  float* mproj = (float*)(Mz);                   // 8 KB
  float* cbuf  = (float*)(Mz + 64 * 1024);       // 256 KB fp32 c-state
  US* hh[2];
  hh[0] = (US*)(Mz + 320 * 1024);                // 128 KB each
  hh[1] = (US*)(Mz + 448 * 1024);

  // ---- prep ----
  cvt16_kernel<<<4096, 256, 0, stream>>>(inputs, flat16, 1048576);
  cvt16_kernel<<<4096, 256, 0, stream>>>(comp, comp16, 1048576);
  mproj_kernel<<<2048, 256, 0, stream>>>(mean, comp, mproj);
  zero_kernel<<<256, 256, 0, stream>>>(cbuf, hh[0]);
  // KT + RTf + WSTf in ONE pass over Kmat+Rmat
  build_weights<<<4096, 256, 0, stream>>>(Rmat, Kmat, KT, RTf, WSTf);

  // xs = (flat - mean) @ comp^T  (2048 x 2048), rows remapped to t*32+b
  gemm128h<2, 0><<<512, 256, 0, stream>>>(flat16, comp16, mproj,
                                          xs16, 16, 2048);
  // zx = xs @ K^T  (2048 x 8192, gate-interleaved cols), fp16 store
  gemm128h<4, 1><<<1024, 256, 0, stream>>>(xs16, KT, nullptr,
                                           zx16, 16, 8192);

  // ---- 64 encoder steps: z = zx[s] + h @ R^T ----
  for (int s = 0; s < 64; ++s) {
    int par = s & 1;
    lstm_step16<<<256, 512, 0, stream>>>(hh[par], RTf,
                                         zx16 + (size_t)s * 32 * 8192,
                                         bias, cbuf, hh[1 - par],
                                         out, -1);
  }
  // ---- 24 decoder steps: z = h @ (K+R)^T ----
  for (int s = 64; s < 88; ++s) {
    int par = s & 1;
    lstm_step16<<<256, 512, 0, stream>>>(hh[par], WSTf,
                                         nullptr,
                                         bias, cbuf, hh[1 - par],
                                         out, s - 64);
  }
}

// Round 15
// 770.722 us; speedup vs baseline: 2.8532x; 1.0089x over previous
//
#include <hip/hip_runtime.h>
#include <math.h>

// ============================================================================
// PCA + LSTM encoder/decoder on MI355X.  (R15 = R14 + build_weights LDS
// column-XOR swizzle [4-way write conflict -> 2-way free] + fused cvt.)
//  - Weights: single fp16, fragment-linear (32 MiB/step @ ~BW floor).
//  - h, xs, zx: single fp16. 256-block step kernel, 8-way split-K, 1 barrier,
//    epilogue inputs prefetched before the MFMA phase.
//  - KT + RTf + WSTf built in ONE pass over Kmat+Rmat.
// ============================================================================

typedef unsigned short US;
typedef __attribute__((ext_vector_type(8))) _Float16 f16x8;
typedef __attribute__((ext_vector_type(4))) float f32x4;

typedef __attribute__((address_space(3))) unsigned int as3_uint;
typedef __attribute__((address_space(1))) unsigned int as1_uint;

#define MFMA16(a, b, c) __builtin_amdgcn_mfma_f32_16x16x32_f16(a, b, c, 0, 0, 0)

__device__ __forceinline__ US f2h(float x) {      // RNE fp32 -> fp16 bits
  _Float16 h = (_Float16)x;
  return __builtin_bit_cast(US, h);
}
__device__ __forceinline__ float h2f(US u) {
  return (float)__builtin_bit_cast(_Float16, u);
}

__device__ __forceinline__ void gl_lds16(const US* g, US* l) {
  __builtin_amdgcn_global_load_lds((const as1_uint*)g, (as3_uint*)l, 16, 0, 0);
}

// ---- fp32 -> fp16 for inputs AND comp in one dispatch -----------------------
__global__ __launch_bounds__(256) void cvt16x2_kernel(
    const float* __restrict__ a, US* __restrict__ oa,
    const float* __restrict__ b, US* __restrict__ ob)
{
  int i = blockIdx.x * 256 + threadIdx.x;       // grid covers 2*1048576
  const float* src = (i < 1048576) ? a : b;
  US* dst = (i < 1048576) ? oa : ob;
  int k = (i < 1048576) ? i : i - 1048576;
  float4 v = reinterpret_cast<const float4*>(src)[k];
  reinterpret_cast<ushort4*>(dst)[k] =
      make_ushort4(f2h(v.x), f2h(v.y), f2h(v.z), f2h(v.w));
}

// ---- zero c (fp32) and initial h (fp16) -------------------------------------
__global__ void zero_kernel(float* __restrict__ c, US* __restrict__ h0)
{
  int i = blockIdx.x * 256 + threadIdx.x;   // grid covers 65536 exactly
  c[i] = 0.f; h0[i] = 0;
}

// ---- mproj[j] = sum_k mean[k] * comp[j][k]  (fp32) --------------------------
__global__ __launch_bounds__(256) void mproj_kernel(
    const float* __restrict__ mean, const float* __restrict__ comp,
    float* __restrict__ mproj)
{
  int j = blockIdx.x;
  const float* row = comp + (size_t)j * 2048;
  float s = 0.f;
  for (int k = threadIdx.x; k < 2048; k += 256) s += mean[k] * row[k];
  __shared__ float ss[4];
  #pragma unroll
  for (int o = 32; o > 0; o >>= 1) s += __shfl_down(s, o, 64);
  if ((threadIdx.x & 63) == 0) ss[threadIdx.x >> 6] = s;
  __syncthreads();
  if (threadIdx.x == 0) mproj[j] = ss[0] + ss[1] + ss[2] + ss[3];
}

// ---- single pass over Kmat+Rmat: emit KT (row-major fp16), RTf, WSTf -------
// j' = 4*u + g <-> source col g*2048+u. frag lin = ((jg*64+kc)*64+l)*8+e.
// LDS tiles use column-XOR swizzle col' = col ^ (((j>>4)&3)<<3): breaks the
// 4-way write conflict (R14: 3.67M conflict cycles) to free 2-way; swz is
// wave-constant on all read paths and preserves 16B alignment (bits>=3 only).
__global__ __launch_bounds__(256) void build_weights(
    const float* __restrict__ Rsrc, const float* __restrict__ Ksrc,
    US* __restrict__ KT, US* __restrict__ tR, US* __restrict__ tS)
{
  __shared__ float tileR[64][68];         // [j'local][k_local^swz(j')]
  __shared__ float tileK[64][68];
  const int ub = blockIdx.x >> 5;         // 0..127 (16 units = 64 j' each)
  const int kb = blockIdx.x & 31;         // 0..31  (64 k each)
  const int u0 = ub * 16, k0 = kb * 64;
  const int j0 = ub * 64;
  const int jg0 = ub * 4, kc0 = kb * 2;
  const int tid = threadIdx.x;

  const int g = tid >> 6, r2 = (tid >> 2) & 15, c4 = tid & 3;
  const int wsz = c4 << 3;                // swz for j = 16*c4 + 4q + g
  #pragma unroll
  for (int rr = 0; rr < 4; ++rr) {
    int row = rr * 16 + r2;
    int rws = row ^ wsz;
    size_t off = (size_t)(k0 + row) * 8192 + g * 2048 + u0 + c4 * 4;
    float4 v = *reinterpret_cast<const float4*>(Rsrc + off);
    float4 w = *reinterpret_cast<const float4*>(Ksrc + off);
    tileR[4 * (c4 * 4 + 0) + g][rws] = v.x;
    tileR[4 * (c4 * 4 + 1) + g][rws] = v.y;
    tileR[4 * (c4 * 4 + 2) + g][rws] = v.z;
    tileR[4 * (c4 * 4 + 3) + g][rws] = v.w;
    tileK[4 * (c4 * 4 + 0) + g][rws] = w.x;
    tileK[4 * (c4 * 4 + 1) + g][rws] = w.y;
    tileK[4 * (c4 * 4 + 2) + g][rws] = w.z;
    tileK[4 * (c4 * 4 + 3) + g][rws] = w.w;
  }
  __syncthreads();

  // KT row-major (for the zx GEMM B operand)
  {
    const int klw = tid & 63, jl0 = tid >> 6;
    #pragma unroll
    for (int r = 0; r < 16; ++r) {
      int jl = r * 4 + jl0;
      int swz = ((jl >> 4) & 3) << 3;
      KT[(size_t)(j0 + jl) * 2048 + (size_t)(k0 + klw)] =
          f2h(tileK[jl][klw ^ swz]);
    }
  }
  // RTf and WSTf fragment-linear
  #pragma unroll
  for (int it = 0; it < 2; ++it) {
    int idx = it * 256 + tid;
    int l = idx & 63, kcl = (idx >> 6) & 1, jgl = idx >> 7;
    int jloc = jgl * 16 + (l & 15);
    int swz = ((jloc >> 4) & 3) << 3;
    int kl = (kcl * 32 + (l >> 4) * 8) ^ swz;   // 8-aligned block relocated
    size_t base = (((size_t)(jg0 + jgl) * 64 + (kc0 + kcl)) * 64 + l) * 8;
    float4 r0 = *reinterpret_cast<const float4*>(&tileR[jloc][kl]);
    float4 r1 = *reinterpret_cast<const float4*>(&tileR[jloc][kl + 4]);
    float4 k0v = *reinterpret_cast<const float4*>(&tileK[jloc][kl]);
    float4 k1v = *reinterpret_cast<const float4*>(&tileK[jloc][kl + 4]);
    float fr[8] = {r0.x, r0.y, r0.z, r0.w, r1.x, r1.y, r1.z, r1.w};
    float fk[8] = {k0v.x, k0v.y, k0v.z, k0v.w, k1v.x, k1v.y, k1v.z, k1v.w};
    unsigned int hr[4], hs[4];
    #pragma unroll
    for (int q = 0; q < 4; ++q) {
      hr[q] = (unsigned int)f2h(fr[2 * q]) |
              ((unsigned int)f2h(fr[2 * q + 1]) << 16);
      hs[q] = (unsigned int)f2h(fr[2 * q] + fk[2 * q]) |
              ((unsigned int)f2h(fr[2 * q + 1] + fk[2 * q + 1]) << 16);
    }
    *reinterpret_cast<uint4*>(tR + base) = make_uint4(hr[0], hr[1], hr[2], hr[3]);
    *reinterpret_cast<uint4*>(tS + base) = make_uint4(hs[0], hs[1], hs[2], hs[3]);
  }
}

// ---- 128-row tiled GEMM, single fp16: C = A @ B^T ---------------------------
// LDS-staged via global_load_lds + XOR swizzle + XCD block swizzle.
// EPI 0: pca (sub mproj, row remap b*64+t -> t*32+b, fp16 store)
// EPI 1: fp16 store at [m][ldo].
template<int NT, int EPI>
__global__ __launch_bounds__(256, 2) void gemm128h(
    const US* __restrict__ A, const US* __restrict__ B,
    const float* __restrict__ mproj,
    US* __restrict__ out0, int MB, int ldo)
{
  constexpr int BN = NT * 32;
  __shared__ US sA[128 * 64];
  __shared__ US sB[BN * 64];
  const int tid = threadIdx.x;
  const int w = tid >> 6, l = tid & 63;
  const int l16 = l & 15, lq = l >> 4;
  const int cpx = gridDim.x >> 3;
  const int swz = (blockIdx.x & 7) * cpx + (blockIdx.x >> 3);
  const int bm = swz % MB, bn = swz / MB;
  const int wm = w & 1, wn = w >> 1;
  const int AR0 = bm * 128, BR0 = bn * BN;

  f32x4 acc[4][NT];
  #pragma unroll
  for (int i = 0; i < 4; ++i)
    #pragma unroll
    for (int j = 0; j < NT; ++j) acc[i][j] = {0.f, 0.f, 0.f, 0.f};

  for (int k0 = 0; k0 < 2048; k0 += 64) {
    {
      #pragma unroll
      for (int i = 0; i < 4; ++i) {          // A tile: 128 rows
        int c = (w * 4 + i) * 64 + l;
        int row = c >> 3, kc = c & 7;
        size_t go = (size_t)(AR0 + row) * 2048 + (k0 + ((kc ^ (row & 7)) << 3));
        gl_lds16(A + go, sA + (w * 4 + i) * 512);
      }
      constexpr int IPW = BN >> 5;           // B tile: BN rows
      #pragma unroll
      for (int i = 0; i < IPW; ++i) {
        int c = (w * IPW + i) * 64 + l;
        int row = c >> 3, kc = c & 7;
        size_t go = (size_t)(BR0 + row) * 2048 + (k0 + ((kc ^ (row & 7)) << 3));
        gl_lds16(B + go, sB + (w * IPW + i) * 512);
      }
    }
    __syncthreads();
    #pragma unroll
    for (int ks = 0; ks < 2; ++ks) {
      const int kb = ks * 64 + lq * 16;
      f16x8 ah[4], bb[NT];
      #pragma unroll
      for (int mt = 0; mt < 4; ++mt) {
        int r = wm * 64 + mt * 16 + l16;
        int off = r * 64 + ((kb ^ ((r & 7) << 4)) >> 1);
        ah[mt] = *reinterpret_cast<const f16x8*>(sA + off);
      }
      #pragma unroll
      for (int nt = 0; nt < NT; ++nt) {
        int r = wn * (BN / 2) + nt * 16 + l16;
        int off = r * 64 + ((kb ^ ((r & 7) << 4)) >> 1);
        bb[nt] = *reinterpret_cast<const f16x8*>(sB + off);
      }
      #pragma unroll
      for (int mt = 0; mt < 4; ++mt)
        #pragma unroll
        for (int nt = 0; nt < NT; ++nt)
          acc[mt][nt] = MFMA16(ah[mt], bb[nt], acc[mt][nt]);
    }
    __syncthreads();
  }

  #pragma unroll
  for (int mt = 0; mt < 4; ++mt)
    #pragma unroll
    for (int nt = 0; nt < NT; ++nt) {
      int j = BR0 + wn * (BN / 2) + nt * 16 + l16;
      float mp = (EPI == 0) ? mproj[j] : 0.f;
      #pragma unroll
      for (int r = 0; r < 4; ++r) {
        int m = AR0 + wm * 64 + mt * 16 + lq * 4 + r;
        float v = acc[mt][nt][r] - mp;
        if constexpr (EPI == 0) {
          int t = m & 63, bb_ = m >> 6;
          out0[(size_t)(t * 32 + bb_) * ldo + j] = f2h(v);
        } else {
          out0[(size_t)m * ldo + j] = f2h(v);
        }
      }
    }
}

// ---- one LSTM step: z = zx + h @ W'^T + bias ; fused cell update -----------
// 256 blocks (block b: 32 j' = 8 units, jg {2b,2b+1}), 512 thr = 8 waves,
// 8-way split-K, ONE barrier. Epilogue inputs (bias/zx/c) prefetched BEFORE
// the MFMA phase so their L3 latency hides under the weight stream.
__global__ __launch_bounds__(512, 4) void lstm_step16(
    const US* __restrict__ hf,                                    // frag (32,2048)
    const US* __restrict__ wf,                                    // frag (8192,2048)
    const US* __restrict__ zx,                                    // fp16 (32,8192) or null
    const float* __restrict__ bias, float* __restrict__ cst,
    US* __restrict__ ho,                                          // frag (32,2048)
    float* __restrict__ pred, int p)
{
  __shared__ float red[8][32][33];        // [kq][j'loc][m]
  const int tid = threadIdx.x;
  const int kq = tid >> 6, l = tid & 63;
  const int b = blockIdx.x;
  const int l16 = l & 15, lq = l >> 4;
  const bool cell = (tid < 256);
  const int m = tid >> 3, ul = tid & 7;   // cell-role (valid when cell)
  const int u = b * 8 + ul;

  // ---- EARLY prefetch of epilogue inputs (latency hides under MFMA phase) --
  float pz0 = 0.f, pz1 = 0.f, pz2 = 0.f, pz3 = 0.f, cprev = 0.f;
  if (cell) {
    pz0 = bias[u];
    pz1 = bias[u + 2048];
    pz2 = bias[u + 4096];
    pz3 = bias[u + 6144];
    if (zx) {
      ushort4 zr = *reinterpret_cast<const ushort4*>(
          zx + (size_t)m * 8192 + (size_t)u * 4);
      pz0 += h2f(zr.x); pz1 += h2f(zr.y); pz2 += h2f(zr.z); pz3 += h2f(zr.w);
    }
    cprev = cst[m * 2048 + u];
  }

  const US* wp0 = wf + (((size_t)(2 * b) * 64 + kq * 8) * 64 + l) * 8;
  const US* wp1 = wp0 + (size_t)64 * 64 * 8;     // jg+1
  const US* ah  = hf + (((size_t)kq * 16) * 64 + l) * 8;

  f32x4 acc00 = {0.f,0.f,0.f,0.f}, acc01 = {0.f,0.f,0.f,0.f};
  f32x4 acc10 = {0.f,0.f,0.f,0.f}, acc11 = {0.f,0.f,0.f,0.f};
  #pragma unroll
  for (int c = 0; c < 8; ++c) {
    f16x8 w0 = *reinterpret_cast<const f16x8*>(wp0 + c * 512);
    f16x8 w1 = *reinterpret_cast<const f16x8*>(wp1 + c * 512);
    f16x8 a0 = *reinterpret_cast<const f16x8*>(ah + c * 1024);
    f16x8 a1 = *reinterpret_cast<const f16x8*>(ah + c * 1024 + 512);
    acc00 = MFMA16(a0, w0, acc00);
    acc10 = MFMA16(a1, w0, acc10);
    acc01 = MFMA16(a0, w1, acc01);
    acc11 = MFMA16(a1, w1, acc11);
  }

  #pragma unroll
  for (int r = 0; r < 4; ++r) {
    red[kq][l16][lq * 4 + r]           = acc00[r];
    red[kq][16 + l16][lq * 4 + r]      = acc01[r];
    red[kq][l16][16 + lq * 4 + r]      = acc10[r];
    red[kq][16 + l16][16 + lq * 4 + r] = acc11[r];
  }
  __syncthreads();

  if (cell) {
    float z0 = pz0, z1 = pz1, z2 = pz2, z3 = pz3;
    #pragma unroll
    for (int q = 0; q < 8; ++q) {
      z0 += red[q][ul * 4 + 0][m];
      z1 += red[q][ul * 4 + 1][m];
      z2 += red[q][ul * 4 + 2][m];
      z3 += red[q][ul * 4 + 3][m];
    }
    float gi = 1.f / (1.f + expf(-z0));
    float gf = 1.f / (1.f + expf(-z1));
    float gg = tanhf(z2);
    float go = 1.f / (1.f + expf(-z3));
    float cn = gf * cprev + gi * gg;
    float hn = go * tanhf(cn);
    cst[m * 2048 + u] = cn;
    // h write in fragment-linear layout for next step's A loads
    int kc = u >> 5, mh = m >> 4;
    int lw = ((u >> 3) & 3) * 16 + (m & 15);
    int e = u & 7;
    ho[(((size_t)kc * 2 + mh) * 64 + lw) * 8 + e] = f2h(hn);
    if (p >= 0) pred[(size_t)(m * 24 + p) * 2048 + u] = hn;
  }
}

// ============================================================================
extern "C" void kernel_launch(void* const* d_in, const int* in_sizes, int n_in,
                              void* d_out, int out_size, void* d_ws, size_t ws_size,
                              hipStream_t stream)
{
  const float* inputs = (const float*)d_in[0];   // (32,64,2048,1)
  const float* comp   = (const float*)d_in[1];   // (2048,2048)
  const float* mean   = (const float*)d_in[2];   // (2048,)
  const float* Kmat   = (const float*)d_in[3];   // (2048,8192)
  const float* Rmat   = (const float*)d_in[4];   // (2048,8192)
  const float* bias   = (const float*)d_in[5];   // (8192,)
  float* out = (float*)d_out;                    // (32,24,2048)

  // ---- workspace layout (~153 MiB, within the proven envelope) ----
  const size_t MiB = 1024 * 1024;
  char* base = (char*)d_ws;
  US* zx16     = (US*)(base);                    // [0,32)   fp16 2048x8192
  US* KT       = (US*)(base + 32 * MiB);         // [32,64)  row-major K^T fp16
  US* RTf      = (US*)(base + 64 * MiB);         // [64,96)  frag R fp16
  US* WSTf     = (US*)(base + 96 * MiB);         // [96,128) frag K+R fp16
  US* flat16   = (US*)(base + 128 * MiB);        // [128,136)
  US* comp16   = (US*)(base + 136 * MiB);        // [136,144)
  US* xs16     = (US*)(base + 144 * MiB);        // [144,152)
  char* Mz = base + 152 * MiB;
  float* mproj = (float*)(Mz);                   // 8 KB
  float* cbuf  = (float*)(Mz + 64 * 1024);       // 256 KB fp32 c-state
  US* hh[2];
  hh[0] = (US*)(Mz + 320 * 1024);                // 128 KB each
  hh[1] = (US*)(Mz + 448 * 1024);

  // ---- prep ----
  cvt16x2_kernel<<<8192, 256, 0, stream>>>(inputs, flat16, comp, comp16);
  mproj_kernel<<<2048, 256, 0, stream>>>(mean, comp, mproj);
  zero_kernel<<<256, 256, 0, stream>>>(cbuf, hh[0]);
  // KT + RTf + WSTf in ONE pass over Kmat+Rmat
  build_weights<<<4096, 256, 0, stream>>>(Rmat, Kmat, KT, RTf, WSTf);

  // xs = (flat - mean) @ comp^T  (2048 x 2048), rows remapped to t*32+b
  gemm128h<2, 0><<<512, 256, 0, stream>>>(flat16, comp16, mproj,
                                          xs16, 16, 2048);
  // zx = xs @ K^T  (2048 x 8192, gate-interleaved cols), fp16 store
  gemm128h<4, 1><<<1024, 256, 0, stream>>>(xs16, KT, nullptr,
                                           zx16, 16, 8192);

  // ---- 64 encoder steps: z = zx[s] + h @ R^T ----
  for (int s = 0; s < 64; ++s) {
    int par = s & 1;
    lstm_step16<<<256, 512, 0, stream>>>(hh[par], RTf,
                                         zx16 + (size_t)s * 32 * 8192,
                                         bias, cbuf, hh[1 - par],
                                         out, -1);
  }
  // ---- 24 decoder steps: z = h @ (K+R)^T ----
  for (int s = 64; s < 88; ++s) {
    int par = s & 1;
    lstm_step16<<<256, 512, 0, stream>>>(hh[par], WSTf,
                                         nullptr,
                                         bias, cbuf, hh[1 - par],
                                         out, s - 64);
  }
}